// Round 1
// baseline (196.268 us; speedup 1.0000x reference)
//
#include <hip/hip_runtime.h>

#define NB 2097152
#define HM 8
#define HP 8
#define NV 2

__device__ __forceinline__ float fexp(float x)     { return __expf(x); }
__device__ __forceinline__ float felu(float x)     { return x > 0.f ? x : fexp(x) - 1.f; }
// NaN-free saturating forms (exp overflow -> correct +/-1 or 0/1 limits)
__device__ __forceinline__ float ftanh(float x)    { return 1.f - 2.f / (fexp(2.f * x) + 1.f); }
__device__ __forceinline__ float fsigmoid(float x) { return 1.f / (1.f + fexp(-x)); }

__global__ __launch_bounds__(256) void odefunc_kernel(
    const float* __restrict__ x,
    const float* __restrict__ mW0, const float* __restrict__ mb0,
    const float* __restrict__ mW1, const float* __restrict__ mb1,
    const float* __restrict__ mW2, const float* __restrict__ mb2,
    const float* __restrict__ pW1, const float* __restrict__ pb1,
    const float* __restrict__ pW2, const float* __restrict__ pb2,
    const float* __restrict__ pW3, const float* __restrict__ pb3,
    float* __restrict__ out)
{
    const int tid = blockIdx.x * blockDim.x + threadIdx.x;
    const int b0  = tid * 2;                    // 2 points per thread

    // coalesced 16B load: x[b0][0..1], x[b0+1][0..1]
    const float4 xv = *reinterpret_cast<const float4*>(x + b0 * 2);
    const float xs[2][2] = {{xv.x, xv.y}, {xv.z, xv.w}};
    float res[2][2];

#pragma unroll
    for (int pt = 0; pt < 2; ++pt) {
        const float x0 = xs[pt][0], x1 = xs[pt][1];

        // ---- m-branch: 2 -> 8 -> 8 -> 4 (ELU) ----
        float h[HM];
#pragma unroll
        for (int o = 0; o < HM; ++o)
            h[o] = felu(mW0[o * 2 + 0] * x0 + mW0[o * 2 + 1] * x1 + mb0[o]);

        float h2[HM];
#pragma unroll
        for (int o = 0; o < HM; ++o) {
            float acc = mb1[o];
#pragma unroll
            for (int i = 0; i < HM; ++i) acc += mW1[o * HM + i] * h[i];
            h2[o] = felu(acc);
        }

        float bm[4];
#pragma unroll
        for (int o = 0; o < 4; ++o) {
            float acc = mb2[o];
#pragma unroll
            for (int i = 0; i < HM; ++i) acc += mW2[o * HM + i] * h2[i];
            bm[o] = acc;
        }
        const float m2   = bm[0] * bm[1] + bm[2] * bm[3];
        const float mag0 = bm[0] * bm[0] + bm[2] * bm[2];
        const float mag3 = bm[1] * bm[1] + bm[3] * bm[3];

        // ---- p-branch: NV potential nets, fwd + analytic input-grad bwd ----
        float g0 = 0.f, g1 = 0.f;
#pragma unroll
        for (int v = 0; v < NV; ++v) {
            const float* W1  = pW1 + v * HP * 2;    // [HP][2]
            const float* B1  = pb1 + v * HP;        // [HP]
            const float* W2  = pW2 + v * HP * HP;   // NLV=1: [HP][HP] (q,p)
            const float* B2  = pb2 + v * HP;        // [HP]
            const float* W3  = pW3 + v * HP;        // [HP]
            const float  B3  = pb3[v];

            float f1[HP];
#pragma unroll
            for (int o = 0; o < HP; ++o)
                f1[o] = ftanh(W1[o * 2 + 0] * x0 + W1[o * 2 + 1] * x1 + B1[o]);

            float f2[HP];
#pragma unroll
            for (int q = 0; q < HP; ++q) {
                float acc = B2[q];
#pragma unroll
                for (int p = 0; p < HP; ++p) acc += W2[q * HP + p] * f1[p];
                f2[q] = ftanh(acc);
            }

            float acc3 = B3;
#pragma unroll
            for (int p = 0; p < HP; ++p) acc3 += W3[p] * f2[p];
            const float f3 = fsigmoid(acc3);
            const float s  = fsigmoid(f3);          // NOTE: double sigmoid, per reference
            const float ss = s * (1.f - s);

            // grad over q with tanh' of f2 folded in
            float gq[HP];
#pragma unroll
            for (int q = 0; q < HP; ++q)
                gq[q] = ss * W3[q] * (1.f - f2[q] * f2[q]);

            // back through W2 (vbq,vqp->vbp), fold tanh' of f1
            float gp[HP];
#pragma unroll
            for (int p = 0; p < HP; ++p) {
                float acc = 0.f;
#pragma unroll
                for (int q = 0; q < HP; ++q) acc += gq[q] * W2[q * HP + p];
                gp[p] = acc * (1.f - f1[p] * f1[p]);
            }

            // back through W1 (vbp,vpi->vbi)
#pragma unroll
            for (int p = 0; p < HP; ++p) {
                g0 += gp[p] * W1[p * 2 + 0];
                g1 += gp[p] * W1[p * 2 + 1];
            }
        }
        g0 *= 0.5f;  // mean over NV=2
        g1 *= 0.5f;

        // out4 = mag * [g0,g1,g0,g1]; out = [o0+o1, o2+o3]
        res[pt][0] = mag0 * g0 + m2 * g1;
        res[pt][1] = m2 * g0 + mag3 * g1;
    }

    // coalesced 16B store: out[b0][0..1], out[b0+1][0..1]
    *reinterpret_cast<float4*>(out + b0 * 2) =
        make_float4(res[0][0], res[0][1], res[1][0], res[1][1]);
}

extern "C" void kernel_launch(void* const* d_in, const int* in_sizes, int n_in,
                              void* d_out, int out_size, void* d_ws, size_t ws_size,
                              hipStream_t stream) {
    // setup_inputs order: t, x, mW0, mb0, mW1, mb1, mW2, mb2, pW1, pb1, pW2, pb2, pW3, pb3
    const float* x   = (const float*)d_in[1];
    const float* mW0 = (const float*)d_in[2];
    const float* mb0 = (const float*)d_in[3];
    const float* mW1 = (const float*)d_in[4];
    const float* mb1 = (const float*)d_in[5];
    const float* mW2 = (const float*)d_in[6];
    const float* mb2 = (const float*)d_in[7];
    const float* pW1 = (const float*)d_in[8];
    const float* pb1 = (const float*)d_in[9];
    const float* pW2 = (const float*)d_in[10];
    const float* pb2 = (const float*)d_in[11];
    const float* pW3 = (const float*)d_in[12];
    const float* pb3 = (const float*)d_in[13];
    float* out = (float*)d_out;

    const int threads = 256;
    const int points_per_thread = 2;
    const int blocks = NB / (threads * points_per_thread);   // 4096
    odefunc_kernel<<<blocks, threads, 0, stream>>>(
        x, mW0, mb0, mW1, mb1, mW2, mb2, pW1, pb1, pW2, pb2, pW3, pb3, out);
}

// Round 2
// 145.407 us; speedup vs baseline: 1.3498x; 1.3498x over previous
//
#include <hip/hip_runtime.h>

#define NB 2097152
#define HM 8
#define HP 8
#define NV 2

// Packed fp32: 2 points per thread, one in each half of a v2 -> v_pk_fma_f32
typedef float v2 __attribute__((ext_vector_type(2)));

static __device__ __forceinline__ v2 splat(float s) { return (v2){s, s}; }
static __device__ __forceinline__ v2 vfma(v2 a, v2 b, v2 c) {
    return __builtin_elementwise_fma(a, b, c);
}
static __device__ __forceinline__ v2 vexp2(v2 x) {
    return (v2){__builtin_amdgcn_exp2f(x.x), __builtin_amdgcn_exp2f(x.y)};
}
static __device__ __forceinline__ v2 vclamp9(v2 x) {
    return (v2){__builtin_amdgcn_fmed3f(x.x, -9.f, 9.f),
                __builtin_amdgcn_fmed3f(x.y, -9.f, 9.f)};
}

// Rational tanh (Eigen fast-tanh coeffs, fp32-accurate on [-9,9], clamped).
// Divisions batched: one v_rcp per 4 tanh per point-half (q in [4.9e-3,1.62],
// product of 4 can't overflow/underflow).
static __device__ __forceinline__ void tanh8(const v2* z, v2* out) {
    const float a1 = 4.89352455891786e-03f, a3 = 6.37261928875436e-04f,
                a5 = 1.48572235717979e-05f, a7 = 5.12229709037114e-08f,
                a9 = -8.60467152213735e-11f, a11 = 2.00018790482477e-13f,
                a13 = -2.76076847742355e-16f;
    const float b0 = 4.89352518554385e-03f, b2 = 2.26843463243900e-03f,
                b4 = 1.18534705686654e-04f, b6 = 1.19825839466702e-06f;
    v2 p[8], q[8];
#pragma unroll
    for (int i = 0; i < 8; ++i) {
        v2 xc = vclamp9(z[i]);
        v2 t  = xc * xc;
        v2 pp = vfma(t, splat(a13), splat(a11));
        pp = vfma(t, pp, splat(a9));
        pp = vfma(t, pp, splat(a7));
        pp = vfma(t, pp, splat(a5));
        pp = vfma(t, pp, splat(a3));
        pp = vfma(t, pp, splat(a1));
        p[i] = pp * xc;
        v2 qq = vfma(t, splat(b6), splat(b4));
        qq = vfma(t, qq, splat(b2));
        q[i] = vfma(t, qq, splat(b0));
    }
#pragma unroll
    for (int g = 0; g < 2; ++g) {
        const v2* qg = q + g * 4;
        const v2* pg = p + g * 4;
        v2* og = out + g * 4;
        v2 ab = qg[0] * qg[1];
        v2 cd = qg[2] * qg[3];
        v2 abcd = ab * cd;
        v2 inv = (v2){__builtin_amdgcn_rcpf(abcd.x), __builtin_amdgcn_rcpf(abcd.y)};
        v2 s  = cd * inv;   // 1/(q0*q1)
        v2 tt = ab * inv;   // 1/(q2*q3)
        og[0] = pg[0] * (qg[1] * s);
        og[1] = pg[1] * (qg[0] * s);
        og[2] = pg[2] * (qg[3] * tt);
        og[3] = pg[3] * (qg[2] * tt);
    }
}

// Branchless packed ELU: elu(x) = max(x, min(e^x - 1, 0)).
// x>0: min(..,0)=0 -> max(x,0)=x.  x<0: e^x-1 in (-1,0) and e^x-1 > x. NaN-free.
static __device__ __forceinline__ void elu8(const v2* z, v2* out) {
    const float L2E = 1.4426950408889634f;
#pragma unroll
    for (int i = 0; i < 8; ++i) {
        v2 e  = vexp2(z[i] * splat(L2E));
        v2 em = e - splat(1.f);
        v2 mn = __builtin_elementwise_min(em, splat(0.f));
        out[i] = __builtin_elementwise_max(z[i], mn);
    }
}

// sigmoid with one rcp shared across the packed point-pair.
// e clamped to <=1e18 so the pair product can't overflow (and no inf*0 NaN).
static __device__ __forceinline__ v2 vsigmoid(v2 z) {
    const float NL2E = -1.4426950408889634f;
    v2 e = vexp2(z * splat(NL2E));               // e^{-z}
    e = __builtin_elementwise_min(e, splat(1e18f));
    v2 d = e + splat(1.f);
    float pr  = d.x * d.y;
    float inv = __builtin_amdgcn_rcpf(pr);
    return (v2){inv * d.y, inv * d.x};           // {1/d.x, 1/d.y}
}

__global__ __launch_bounds__(256) void odefunc_kernel(
    const float* __restrict__ x,
    const float* __restrict__ mW0, const float* __restrict__ mb0,
    const float* __restrict__ mW1, const float* __restrict__ mb1,
    const float* __restrict__ mW2, const float* __restrict__ mb2,
    const float* __restrict__ pW1, const float* __restrict__ pb1,
    const float* __restrict__ pW2, const float* __restrict__ pb2,
    const float* __restrict__ pW3, const float* __restrict__ pb3,
    float* __restrict__ out)
{
    const int tid = blockIdx.x * blockDim.x + threadIdx.x;
    const int b0  = tid * 2;

    const float4 xv = *reinterpret_cast<const float4*>(x + b0 * 2);
    const v2 x0 = (v2){xv.x, xv.z};   // dim-0 of point A, point B
    const v2 x1 = (v2){xv.y, xv.w};   // dim-1
    const v2 one = splat(1.f);

    // ---- m-branch: 2 -> 8 -> 8 -> 4, ELU ----
    v2 z[HM], h[HM], h2[HM];
#pragma unroll
    for (int o = 0; o < HM; ++o)
        z[o] = vfma(splat(mW0[o * 2]), x0,
                    vfma(splat(mW0[o * 2 + 1]), x1, splat(mb0[o])));
    elu8(z, h);
#pragma unroll
    for (int o = 0; o < HM; ++o) {
        v2 acc = splat(mb1[o]);
#pragma unroll
        for (int i = 0; i < HM; ++i) acc = vfma(splat(mW1[o * HM + i]), h[i], acc);
        z[o] = acc;
    }
    elu8(z, h2);

    v2 bm[4];
#pragma unroll
    for (int o = 0; o < 4; ++o) {
        v2 acc = splat(mb2[o]);
#pragma unroll
        for (int i = 0; i < HM; ++i) acc = vfma(splat(mW2[o * HM + i]), h2[i], acc);
        bm[o] = acc;
    }
    const v2 m2   = bm[0] * bm[1] + bm[2] * bm[3];
    const v2 mag0 = bm[0] * bm[0] + bm[2] * bm[2];
    const v2 mag3 = bm[1] * bm[1] + bm[3] * bm[3];

    // ---- p-branch: NV nets, fwd + analytic input-grad bwd ----
    v2 g0 = splat(0.f), g1 = splat(0.f);
#pragma unroll
    for (int v = 0; v < NV; ++v) {
        const float* W1 = pW1 + v * HP * 2;
        const float* B1 = pb1 + v * HP;
        const float* W2 = pW2 + v * HP * HP;
        const float* B2 = pb2 + v * HP;
        const float* W3 = pW3 + v * HP;
        const float  B3 = pb3[v];

        v2 zf[HP], f1[HP], f2[HP];
#pragma unroll
        for (int o = 0; o < HP; ++o)
            zf[o] = vfma(splat(W1[o * 2]), x0,
                         vfma(splat(W1[o * 2 + 1]), x1, splat(B1[o])));
        tanh8(zf, f1);

#pragma unroll
        for (int q = 0; q < HP; ++q) {
            v2 acc = splat(B2[q]);
#pragma unroll
            for (int p = 0; p < HP; ++p) acc = vfma(splat(W2[q * HP + p]), f1[p], acc);
            zf[q] = acc;
        }
        tanh8(zf, f2);

        v2 acc3 = splat(B3);
#pragma unroll
        for (int p = 0; p < HP; ++p) acc3 = vfma(splat(W3[p]), f2[p], acc3);
        const v2 f3 = vsigmoid(acc3);
        const v2 s  = vsigmoid(f3);          // double sigmoid per reference
        const v2 ss = s * (one - s);

        // gq = W3 .* (1 - f2^2)   (ss folded in at the very end)
        v2 gq[HP];
#pragma unroll
        for (int q = 0; q < HP; ++q)
            gq[q] = splat(W3[q]) * vfma(-f2[q], f2[q], one);

        v2 gp[HP];
#pragma unroll
        for (int p = 0; p < HP; ++p) {
            v2 acc = splat(0.f);
#pragma unroll
            for (int q = 0; q < HP; ++q) acc = vfma(gq[q], splat(W2[q * HP + p]), acc);
            gp[p] = acc * vfma(-f1[p], f1[p], one);
        }

        v2 gi0 = splat(0.f), gi1 = splat(0.f);
#pragma unroll
        for (int p = 0; p < HP; ++p) {
            gi0 = vfma(gp[p], splat(W1[p * 2]), gi0);
            gi1 = vfma(gp[p], splat(W1[p * 2 + 1]), gi1);
        }
        g0 = vfma(ss, gi0, g0);
        g1 = vfma(ss, gi1, g1);
    }
    g0 = g0 * splat(0.5f);   // mean over NV=2
    g1 = g1 * splat(0.5f);

    const v2 r0 = mag0 * g0 + m2 * g1;
    const v2 r1 = m2 * g0 + mag3 * g1;

    *reinterpret_cast<float4*>(out + b0 * 2) = make_float4(r0.x, r1.x, r0.y, r1.y);
}

extern "C" void kernel_launch(void* const* d_in, const int* in_sizes, int n_in,
                              void* d_out, int out_size, void* d_ws, size_t ws_size,
                              hipStream_t stream) {
    const float* x   = (const float*)d_in[1];
    const float* mW0 = (const float*)d_in[2];
    const float* mb0 = (const float*)d_in[3];
    const float* mW1 = (const float*)d_in[4];
    const float* mb1 = (const float*)d_in[5];
    const float* mW2 = (const float*)d_in[6];
    const float* mb2 = (const float*)d_in[7];
    const float* pW1 = (const float*)d_in[8];
    const float* pb1 = (const float*)d_in[9];
    const float* pW2 = (const float*)d_in[10];
    const float* pb2 = (const float*)d_in[11];
    const float* pW3 = (const float*)d_in[12];
    const float* pb3 = (const float*)d_in[13];
    float* out = (float*)d_out;

    const int threads = 256;
    const int blocks  = NB / (threads * 2);   // 2 points/thread -> 4096 blocks
    odefunc_kernel<<<blocks, threads, 0, stream>>>(
        x, mW0, mb0, mW1, mb1, mW2, mb2, pW1, pb1, pW2, pb2, pW3, pb3, out);
}

// Round 3
// 144.023 us; speedup vs baseline: 1.3627x; 1.0096x over previous
//
#include <hip/hip_runtime.h>

#define NB 2097152
#define HM 8
#define HP 8
#define NV 2

// Packed fp32: one point-pair per v2 register (v_pk_* ops), 2 pairs per thread
// for ILP (round-2 showed VALUBusy 73% -> dependency-stall at low chain count).
typedef float v2 __attribute__((ext_vector_type(2)));

static __device__ __forceinline__ v2 splat(float s) { return (v2){s, s}; }
static __device__ __forceinline__ v2 vfma(v2 a, v2 b, v2 c) {
    return __builtin_elementwise_fma(a, b, c);
}
static __device__ __forceinline__ v2 vexp2(v2 x) {
    return (v2){__builtin_amdgcn_exp2f(x.x), __builtin_amdgcn_exp2f(x.y)};
}

// tanh(x) = 1 - 2/(e^{2x}+1). e clamped <=1e8: keeps the 4-way rcp-batch
// product <=1e32 (no overflow) and costs only ~2e-8 abs error at saturation.
// x<0: exp2 underflows to 0 -> d=1 -> tanh=-1 exactly. NaN-free.
// One v_rcp per 4 tanh per point-half.
static __device__ __forceinline__ void tanh8(const v2* z, v2* out) {
    const float TL2E = 2.8853900817779268f;   // 2*log2(e)
    v2 d[8];
#pragma unroll
    for (int i = 0; i < 8; ++i) {
        v2 e = vexp2(z[i] * splat(TL2E));
        e = __builtin_elementwise_min(e, splat(1e8f));
        d[i] = e + splat(1.f);
    }
#pragma unroll
    for (int g = 0; g < 2; ++g) {
        const v2* dg = d + 4 * g;
        v2* og = out + 4 * g;
        v2 ab = dg[0] * dg[1];
        v2 cd = dg[2] * dg[3];
        v2 abcd = ab * cd;
        v2 inv = (v2){__builtin_amdgcn_rcpf(abcd.x), __builtin_amdgcn_rcpf(abcd.y)};
        v2 s = cd * inv;   // 1/(d0*d1)
        v2 t = ab * inv;   // 1/(d2*d3)
        og[0] = vfma(dg[1] * s, splat(-2.f), splat(1.f));
        og[1] = vfma(dg[0] * s, splat(-2.f), splat(1.f));
        og[2] = vfma(dg[3] * t, splat(-2.f), splat(1.f));
        og[3] = vfma(dg[2] * t, splat(-2.f), splat(1.f));
    }
}

// Branchless packed ELU: elu(x) = max(x, min(e^x - 1, 0)). NaN-free.
static __device__ __forceinline__ void elu8(const v2* z, v2* out) {
    const float L2E = 1.4426950408889634f;
#pragma unroll
    for (int i = 0; i < 8; ++i) {
        v2 e  = vexp2(z[i] * splat(L2E));
        v2 em = e - splat(1.f);
        v2 mn = __builtin_elementwise_min(em, splat(0.f));
        out[i] = __builtin_elementwise_max(z[i], mn);
    }
}

// sigmoid with one rcp shared across the packed point-pair (e clamped so the
// pair product can't overflow; adds <=1e-8 abs error).
static __device__ __forceinline__ v2 vsigmoid(v2 z) {
    const float NL2E = -1.4426950408889634f;
    v2 e = vexp2(z * splat(NL2E));               // e^{-z}
    e = __builtin_elementwise_min(e, splat(1e8f));
    v2 d = e + splat(1.f);
    float pr  = d.x * d.y;
    float inv = __builtin_amdgcn_rcpf(pr);
    return (v2){inv * d.y, inv * d.x};           // {1/d.x, 1/d.y}
}

// Full pipeline for one packed point-pair.
static __device__ __forceinline__ void compute_pair(
    v2 x0, v2 x1,
    const float* __restrict__ mW0, const float* __restrict__ mb0,
    const float* __restrict__ mW1, const float* __restrict__ mb1,
    const float* __restrict__ mW2, const float* __restrict__ mb2,
    const float* __restrict__ pW1, const float* __restrict__ pb1,
    const float* __restrict__ pW2, const float* __restrict__ pb2,
    const float* __restrict__ pW3, const float* __restrict__ pb3,
    v2& r0, v2& r1)
{
    const v2 one = splat(1.f);

    // ---- m-branch: 2 -> 8 -> 8 -> 4, ELU ----
    v2 z[HM], h[HM], h2[HM];
#pragma unroll
    for (int o = 0; o < HM; ++o)
        z[o] = vfma(splat(mW0[o * 2]), x0,
                    vfma(splat(mW0[o * 2 + 1]), x1, splat(mb0[o])));
    elu8(z, h);
#pragma unroll
    for (int o = 0; o < HM; ++o) {
        v2 acc = splat(mb1[o]);
#pragma unroll
        for (int i = 0; i < HM; ++i) acc = vfma(splat(mW1[o * HM + i]), h[i], acc);
        z[o] = acc;
    }
    elu8(z, h2);

    v2 bm[4];
#pragma unroll
    for (int o = 0; o < 4; ++o) {
        v2 acc = splat(mb2[o]);
#pragma unroll
        for (int i = 0; i < HM; ++i) acc = vfma(splat(mW2[o * HM + i]), h2[i], acc);
        bm[o] = acc;
    }
    const v2 m2   = bm[0] * bm[1] + bm[2] * bm[3];
    const v2 mag0 = bm[0] * bm[0] + bm[2] * bm[2];
    const v2 mag3 = bm[1] * bm[1] + bm[3] * bm[3];

    // ---- p-branch: NV nets, fwd + analytic input-grad bwd ----
    v2 g0 = splat(0.f), g1 = splat(0.f);
#pragma unroll
    for (int v = 0; v < NV; ++v) {
        const float* W1 = pW1 + v * HP * 2;
        const float* B1 = pb1 + v * HP;
        const float* W2 = pW2 + v * HP * HP;
        const float* B2 = pb2 + v * HP;
        const float* W3 = pW3 + v * HP;
        const float  B3 = pb3[v];

        v2 zf[HP], f1[HP], f2[HP];
#pragma unroll
        for (int o = 0; o < HP; ++o)
            zf[o] = vfma(splat(W1[o * 2]), x0,
                         vfma(splat(W1[o * 2 + 1]), x1, splat(B1[o])));
        tanh8(zf, f1);

#pragma unroll
        for (int q = 0; q < HP; ++q) {
            v2 acc = splat(B2[q]);
#pragma unroll
            for (int p = 0; p < HP; ++p) acc = vfma(splat(W2[q * HP + p]), f1[p], acc);
            zf[q] = acc;
        }
        tanh8(zf, f2);

        v2 acc3 = splat(B3);
#pragma unroll
        for (int p = 0; p < HP; ++p) acc3 = vfma(splat(W3[p]), f2[p], acc3);
        const v2 f3 = vsigmoid(acc3);
        const v2 s  = vsigmoid(f3);          // double sigmoid per reference
        const v2 ss = s * (one - s);

        v2 gq[HP];
#pragma unroll
        for (int q = 0; q < HP; ++q)
            gq[q] = splat(W3[q]) * vfma(-f2[q], f2[q], one);

        v2 gp[HP];
#pragma unroll
        for (int p = 0; p < HP; ++p) {
            v2 acc = splat(0.f);
#pragma unroll
            for (int q = 0; q < HP; ++q) acc = vfma(gq[q], splat(W2[q * HP + p]), acc);
            gp[p] = acc * vfma(-f1[p], f1[p], one);
        }

        v2 gi0 = splat(0.f), gi1 = splat(0.f);
#pragma unroll
        for (int p = 0; p < HP; ++p) {
            gi0 = vfma(gp[p], splat(W1[p * 2]), gi0);
            gi1 = vfma(gp[p], splat(W1[p * 2 + 1]), gi1);
        }
        g0 = vfma(ss, gi0, g0);
        g1 = vfma(ss, gi1, g1);
    }
    g0 = g0 * splat(0.5f);   // mean over NV=2
    g1 = g1 * splat(0.5f);

    r0 = mag0 * g0 + m2 * g1;
    r1 = m2 * g0 + mag3 * g1;
}

__global__ __launch_bounds__(256) void odefunc_kernel(
    const float* __restrict__ x,
    const float* __restrict__ mW0, const float* __restrict__ mb0,
    const float* __restrict__ mW1, const float* __restrict__ mb1,
    const float* __restrict__ mW2, const float* __restrict__ mb2,
    const float* __restrict__ pW1, const float* __restrict__ pb1,
    const float* __restrict__ pW2, const float* __restrict__ pb2,
    const float* __restrict__ pW3, const float* __restrict__ pb3,
    float* __restrict__ out)
{
    const int tid = blockIdx.x * blockDim.x + threadIdx.x;
    const int b0  = tid * 4;                    // 4 points per thread

    const float4 xvA = *reinterpret_cast<const float4*>(x + b0 * 2);
    const float4 xvB = *reinterpret_cast<const float4*>(x + b0 * 2 + 4);

    v2 r0A, r1A, r0B, r1B;
    compute_pair((v2){xvA.x, xvA.z}, (v2){xvA.y, xvA.w},
                 mW0, mb0, mW1, mb1, mW2, mb2,
                 pW1, pb1, pW2, pb2, pW3, pb3, r0A, r1A);
    compute_pair((v2){xvB.x, xvB.z}, (v2){xvB.y, xvB.w},
                 mW0, mb0, mW1, mb1, mW2, mb2,
                 pW1, pb1, pW2, pb2, pW3, pb3, r0B, r1B);

    *reinterpret_cast<float4*>(out + b0 * 2)     = make_float4(r0A.x, r1A.x, r0A.y, r1A.y);
    *reinterpret_cast<float4*>(out + b0 * 2 + 4) = make_float4(r0B.x, r1B.x, r0B.y, r1B.y);
}

extern "C" void kernel_launch(void* const* d_in, const int* in_sizes, int n_in,
                              void* d_out, int out_size, void* d_ws, size_t ws_size,
                              hipStream_t stream) {
    const float* x   = (const float*)d_in[1];
    const float* mW0 = (const float*)d_in[2];
    const float* mb0 = (const float*)d_in[3];
    const float* mW1 = (const float*)d_in[4];
    const float* mb1 = (const float*)d_in[5];
    const float* mW2 = (const float*)d_in[6];
    const float* mb2 = (const float*)d_in[7];
    const float* pW1 = (const float*)d_in[8];
    const float* pb1 = (const float*)d_in[9];
    const float* pW2 = (const float*)d_in[10];
    const float* pb2 = (const float*)d_in[11];
    const float* pW3 = (const float*)d_in[12];
    const float* pb3 = (const float*)d_in[13];
    float* out = (float*)d_out;

    const int threads = 256;
    const int blocks  = NB / (threads * 4);   // 4 points/thread -> 2048 blocks
    odefunc_kernel<<<blocks, threads, 0, stream>>>(
        x, mW0, mb0, mW1, mb1, mW2, mb2, pW1, pb1, pW2, pb2, pW3, pb3, out);
}

// Round 5
// 137.528 us; speedup vs baseline: 1.4271x; 1.0472x over previous
//
#include <hip/hip_runtime.h>

#define NB 2097152
#define HM 8
#define HP 8
#define NV 2

// NOTE: clang's amdgcn builtins (cvt_pkrtz, fdot2) use __fp16 vectors, not _Float16.
typedef __fp16 h2 __attribute__((ext_vector_type(2)));

// Packed-weight workspace layout (32-bit words; h2 pairs unless noted f32):
//   0: mW0p[8]           pairs over i                      (unscaled)
//   8: mW1p[8][4]        pairs over i                      (unscaled)
//  40: mW2p[4][4]        pairs over i                      (unscaled)
//  56: pW1f[v][8]        pairs over i, scaled 2*log2(e)    (tanh fold)
//  72: pW2f[v][8][4]     pairs over p, scaled 2*log2(e)
// 136: pW3f[v][4]        pairs over p, scaled -log2(e)     (sigmoid fold)
// 144: pW2T[v][8][4]     pairs over q (transposed, unscaled, for gp)
// 208: pW1T[v][2][4]     pairs over p (transposed, unscaled, for gi)
// 224: f32 pb1s[16]      = 2*log2(e)*pb1
// 240: f32 pb2s[16]      = 2*log2(e)*pb2
// 256: f32 pb3s[2]       = -log2(e)*pb3
#define OFF_MW0   0
#define OFF_MW1   8
#define OFF_MW2   40
#define OFF_PW1F  56
#define OFF_PW2F  72
#define OFF_PW3F  136
#define OFF_PW2T  144
#define OFF_PW1T  208
#define FOFF_PB1  224
#define FOFF_PB2  240
#define FOFF_PB3  256

#define L2E  1.4426950408889634f
#define TL2E 2.8853901635333640f   // 2*log2(e)

static __device__ __forceinline__ h2 pk(float a, float b) {
    return __builtin_amdgcn_cvt_pkrtz(a, b);
}
static __device__ __forceinline__ float fdot2(h2 a, h2 b, float c) {
    return __builtin_amdgcn_fdot2(a, b, c, false);   // v_dot2_f32_f16
}
static __device__ __forceinline__ unsigned h2bits(h2 v) {
    union { h2 h; unsigned u; } c; c.h = v; return c.u;
}
static __device__ __forceinline__ h2 bits2h(unsigned u) {
    union { h2 h; unsigned u; } c; c.u = u; return c.h;
}

// ---------------- prep: pack/scale weights into ws ----------------
__global__ void prep_kernel(
    const float* __restrict__ mW0, const float* __restrict__ mW1,
    const float* __restrict__ mW2,
    const float* __restrict__ pW1, const float* __restrict__ pb1,
    const float* __restrict__ pW2, const float* __restrict__ pb2,
    const float* __restrict__ pW3, const float* __restrict__ pb3,
    unsigned* __restrict__ ws)
{
    const int t = threadIdx.x;           // 64 threads
    float* wf = (float*)ws;

    if (t < 8)  ws[OFF_MW0 + t] = h2bits(pk(mW0[t*2], mW0[t*2+1]));
    if (t < 32) { int o = t >> 2, k = t & 3;
        ws[OFF_MW1 + t] = h2bits(pk(mW1[o*8 + 2*k], mW1[o*8 + 2*k + 1])); }
    if (t < 16) { int o = t >> 2, k = t & 3;
        ws[OFF_MW2 + t] = h2bits(pk(mW2[o*8 + 2*k], mW2[o*8 + 2*k + 1])); }
    // pW1 flat [v][o][i] = v*16 + o*2 + i ; t = v*8+o
    if (t < 16) ws[OFF_PW1F + t] = h2bits(pk(TL2E*pW1[t*2], TL2E*pW1[t*2+1]));
    { // pW2 fwd, pairs over p, scaled. t = v*32 + q*4 + k
      int v = t >> 5, q = (t >> 2) & 7, k = t & 3;
      ws[OFF_PW2F + t] = h2bits(pk(TL2E*pW2[v*64 + q*8 + 2*k],
                                   TL2E*pW2[v*64 + q*8 + 2*k + 1])); }
    if (t < 8) { int v = t >> 2, k = t & 3;
        ws[OFF_PW3F + t] = h2bits(pk(-L2E*pW3[v*8 + 2*k], -L2E*pW3[v*8 + 2*k + 1])); }
    { // pW2 transposed (pairs over q, unscaled). t = v*32 + p*4 + k
      int v = t >> 5, p = (t >> 2) & 7, k = t & 3;
      ws[OFF_PW2T + t] = h2bits(pk(pW2[v*64 + (2*k)*8 + p],
                                   pW2[v*64 + (2*k+1)*8 + p])); }
    // pW1 transposed (pairs over p). t = v*8 + i*4 + k
    if (t < 16) { int v = t >> 3, i = (t >> 2) & 1, k = t & 3;
        ws[OFF_PW1T + t] = h2bits(pk(pW1[v*16 + (2*k)*2 + i],
                                     pW1[v*16 + (2*k+1)*2 + i])); }
    if (t < 16) wf[FOFF_PB1 + t] = TL2E * pb1[t];
    if (t < 16) wf[FOFF_PB2 + t] = TL2E * pb2[t];
    if (t < 2)  wf[FOFF_PB3 + t] = -L2E * pb3[t];
}

// ---------------- activations (scalar f32) ----------------
// in: z already scaled by 2*log2(e) (folded into weights). out: tanh.
// One v_rcp per 4 tanh (batched); e clamped so 4-product <= ~1e32.
static __device__ __forceinline__ void tanh8s(float* d) {
#pragma unroll
    for (int i = 0; i < 8; ++i) {
        float e = __builtin_amdgcn_exp2f(d[i]);
        d[i] = fminf(e, 1e8f) + 1.f;
    }
#pragma unroll
    for (int g = 0; g < 2; ++g) {
        float* q = d + 4*g;
        float ab = q[0]*q[1], cd = q[2]*q[3];
        float inv = __builtin_amdgcn_rcpf(ab*cd);
        float s = cd*inv, t = ab*inv;
        float r0 = q[1]*s, r1 = q[0]*s, r2 = q[3]*t, r3 = q[2]*t;
        q[0] = fmaf(r0, -2.f, 1.f);
        q[1] = fmaf(r1, -2.f, 1.f);
        q[2] = fmaf(r2, -2.f, 1.f);
        q[3] = fmaf(r3, -2.f, 1.f);
    }
}
// elu(x) = max(x, min(e^x - 1, 0)); NaN-free, branchless.
static __device__ __forceinline__ void elu8s(const float* z, float* h) {
#pragma unroll
    for (int i = 0; i < 8; ++i) {
        float e = __builtin_amdgcn_exp2f(z[i] * L2E);
        h[i] = fmaxf(z[i], fminf(e - 1.f, 0.f));
    }
}

// ---------------- one point, scalar f32 state + f16 dot2 matvecs ----------------
static __device__ __forceinline__ void compute_point(
    float x0, float x1,
    const unsigned* __restrict__ W, const float* __restrict__ Wf,
    const float* __restrict__ mb0, const float* __restrict__ mb1,
    const float* __restrict__ mb2, const float* __restrict__ pW3,
    float& r0, float& r1)
{
    const h2 xh = pk(x0, x1);

    // ---- m-branch: 2 -> 8 -> 8 -> 4, ELU ----
    float z[8], h[8];
#pragma unroll
    for (int o = 0; o < 8; ++o) z[o] = fdot2(xh, bits2h(W[OFF_MW0 + o]), mb0[o]);
    elu8s(z, h);
    h2 hp[4];
#pragma unroll
    for (int k = 0; k < 4; ++k) hp[k] = pk(h[2*k], h[2*k+1]);
#pragma unroll
    for (int o = 0; o < 8; ++o) {
        float a = mb1[o];
#pragma unroll
        for (int k = 0; k < 4; ++k) a = fdot2(hp[k], bits2h(W[OFF_MW1 + o*4 + k]), a);
        z[o] = a;
    }
    elu8s(z, h);
#pragma unroll
    for (int k = 0; k < 4; ++k) hp[k] = pk(h[2*k], h[2*k+1]);
    float bm[4];
#pragma unroll
    for (int o = 0; o < 4; ++o) {
        float a = mb2[o];
#pragma unroll
        for (int k = 0; k < 4; ++k) a = fdot2(hp[k], bits2h(W[OFF_MW2 + o*4 + k]), a);
        bm[o] = a;
    }
    const float m2   = bm[0]*bm[1] + bm[2]*bm[3];
    const float mag0 = bm[0]*bm[0] + bm[2]*bm[2];
    const float mag3 = bm[1]*bm[1] + bm[3]*bm[3];

    // ---- p-branch: NV nets, fwd + analytic input-grad bwd ----
    float g0 = 0.f, g1 = 0.f;
#pragma unroll
    for (int v = 0; v < NV; ++v) {
        float f1[8], f2[8];
#pragma unroll
        for (int o = 0; o < 8; ++o)
            f1[o] = fdot2(xh, bits2h(W[OFF_PW1F + v*8 + o]), Wf[FOFF_PB1 + v*8 + o]);
        tanh8s(f1);
        h2 f1p[4];
#pragma unroll
        for (int k = 0; k < 4; ++k) f1p[k] = pk(f1[2*k], f1[2*k+1]);

#pragma unroll
        for (int q = 0; q < 8; ++q) {
            float a = Wf[FOFF_PB2 + v*8 + q];
#pragma unroll
            for (int k = 0; k < 4; ++k)
                a = fdot2(f1p[k], bits2h(W[OFF_PW2F + v*32 + q*4 + k]), a);
            f2[q] = a;
        }
        tanh8s(f2);
        h2 f2p[4];
#pragma unroll
        for (int k = 0; k < 4; ++k) f2p[k] = pk(f2[2*k], f2[2*k+1]);

        float z3 = Wf[FOFF_PB3 + v];                     // pre-scaled by -log2(e)
#pragma unroll
        for (int k = 0; k < 4; ++k)
            z3 = fdot2(f2p[k], bits2h(W[OFF_PW3F + v*4 + k]), z3);
        const float e1 = __builtin_amdgcn_exp2f(z3);     // e^{-z3}, bounded (|z3|<~20)
        const float f3 = __builtin_amdgcn_rcpf(e1 + 1.f);
        const float e2 = __builtin_amdgcn_exp2f(f3 * (-L2E));  // f3 in (0,1)
        const float s  = __builtin_amdgcn_rcpf(e2 + 1.f);
        const float ss = s * (1.f - s);

        // gq = W3 .* (1 - f2^2), packed f16
        h2 gqp[4];
#pragma unroll
        for (int k = 0; k < 4; ++k) {
            float a = pW3[v*8 + 2*k]   * fmaf(-f2[2*k],   f2[2*k],   1.f);
            float b = pW3[v*8 + 2*k+1] * fmaf(-f2[2*k+1], f2[2*k+1], 1.f);
            gqp[k] = pk(a, b);
        }
        // gp[p] = (sum_q gq[q] W2[q][p]) * (1 - f1[p]^2), packed f16
        float gp[8];
#pragma unroll
        for (int p = 0; p < 8; ++p) {
            float a = 0.f;
#pragma unroll
            for (int k = 0; k < 4; ++k)
                a = fdot2(gqp[k], bits2h(W[OFF_PW2T + v*32 + p*4 + k]), a);
            gp[p] = a * fmaf(-f1[p], f1[p], 1.f);
        }
        h2 gpp[4];
#pragma unroll
        for (int k = 0; k < 4; ++k) gpp[k] = pk(gp[2*k], gp[2*k+1]);

        float gi0 = 0.f, gi1 = 0.f;
#pragma unroll
        for (int k = 0; k < 4; ++k) {
            gi0 = fdot2(gpp[k], bits2h(W[OFF_PW1T + v*8 + k]),     gi0);
            gi1 = fdot2(gpp[k], bits2h(W[OFF_PW1T + v*8 + 4 + k]), gi1);
        }
        g0 = fmaf(ss, gi0, g0);
        g1 = fmaf(ss, gi1, g1);
    }
    g0 *= 0.5f;   // mean over NV=2
    g1 *= 0.5f;

    r0 = mag0*g0 + m2*g1;
    r1 = m2*g0 + mag3*g1;
}

__global__ __launch_bounds__(256) void odefunc_kernel(
    const float* __restrict__ x,
    const unsigned* __restrict__ W,
    const float* __restrict__ mb0, const float* __restrict__ mb1,
    const float* __restrict__ mb2, const float* __restrict__ pW3,
    float* __restrict__ out)
{
    const int tid = blockIdx.x * blockDim.x + threadIdx.x;
    const int b0  = tid * 2;                 // 2 points per thread (ILP=2 chains)
    const float* Wf = (const float*)W;

    const float4 xv = *reinterpret_cast<const float4*>(x + b0 * 2);
    float r0A, r1A, r0B, r1B;
    compute_point(xv.x, xv.y, W, Wf, mb0, mb1, mb2, pW3, r0A, r1A);
    compute_point(xv.z, xv.w, W, Wf, mb0, mb1, mb2, pW3, r0B, r1B);

    *reinterpret_cast<float4*>(out + b0 * 2) = make_float4(r0A, r1A, r0B, r1B);
}

extern "C" void kernel_launch(void* const* d_in, const int* in_sizes, int n_in,
                              void* d_out, int out_size, void* d_ws, size_t ws_size,
                              hipStream_t stream) {
    // order: t, x, mW0, mb0, mW1, mb1, mW2, mb2, pW1, pb1, pW2, pb2, pW3, pb3
    const float* x   = (const float*)d_in[1];
    const float* mW0 = (const float*)d_in[2];
    const float* mb0 = (const float*)d_in[3];
    const float* mW1 = (const float*)d_in[4];
    const float* mb1 = (const float*)d_in[5];
    const float* mW2 = (const float*)d_in[6];
    const float* mb2 = (const float*)d_in[7];
    const float* pW1 = (const float*)d_in[8];
    const float* pb1 = (const float*)d_in[9];
    const float* pW2 = (const float*)d_in[10];
    const float* pb2 = (const float*)d_in[11];
    const float* pW3 = (const float*)d_in[12];
    const float* pb3 = (const float*)d_in[13];
    unsigned* ws = (unsigned*)d_ws;
    float* out = (float*)d_out;

    prep_kernel<<<1, 64, 0, stream>>>(mW0, mW1, mW2, pW1, pb1, pW2, pb2, pW3, pb3, ws);

    const int threads = 256;
    const int blocks  = NB / (threads * 2);   // 4096 blocks
    odefunc_kernel<<<blocks, threads, 0, stream>>>(x, ws, mb0, mb1, mb2, pW3, out);
}

// Round 6
// 137.335 us; speedup vs baseline: 1.4291x; 1.0014x over previous
//
#include <hip/hip_runtime.h>

#define NB 2097152
#define HM 8
#define HP 8
#define NV 2

// NOTE: clang's amdgcn builtins (cvt_pkrtz, fdot2) use __fp16 vectors.
typedef __fp16 h2 __attribute__((ext_vector_type(2)));

// Packed-weight workspace layout (32-bit words; h2 pairs unless noted f32):
#define OFF_MW0   0     // mW0p[8]        pairs over i (unscaled)
#define OFF_MW1   8     // mW1p[8][4]     pairs over i
#define OFF_MW2   40    // mW2p[4][4]     pairs over i
#define OFF_PW1F  56    // pW1f[v][8]     pairs over i, scaled 2*log2(e)
#define OFF_PW2F  72    // pW2f[v][8][4]  pairs over p, scaled 2*log2(e)
#define OFF_PW3F  136   // pW3f[v][4]     pairs over p, scaled -log2(e)
#define OFF_PW2T  144   // pW2T[v][8][4]  pairs over q (transposed, unscaled)
#define OFF_PW1T  208   // pW1T[v][2][4]  pairs over p (transposed, unscaled)
#define FOFF_PB1  224   // f32 2*log2(e)*pb1 [16]
#define FOFF_PB2  240   // f32 2*log2(e)*pb2 [16]
#define FOFF_PB3  256   // f32 -log2(e)*pb3 [2]

#define L2E  1.4426950408889634f
#define TL2E 2.8853901635333640f   // 2*log2(e)

static __device__ __forceinline__ h2 pk(float a, float b) {
    return __builtin_amdgcn_cvt_pkrtz(a, b);
}
static __device__ __forceinline__ float fdot2(h2 a, h2 b, float c) {
    return __builtin_amdgcn_fdot2(a, b, c, false);   // v_dot2_f32_f16
}
static __device__ __forceinline__ unsigned h2bits(h2 v) {
    union { h2 h; unsigned u; } c; c.h = v; return c.u;
}
static __device__ __forceinline__ h2 bits2h(unsigned u) {
    union { h2 h; unsigned u; } c; c.u = u; return c.h;
}

// ---------------- prep: pack/scale weights into ws ----------------
__global__ void prep_kernel(
    const float* __restrict__ mW0, const float* __restrict__ mW1,
    const float* __restrict__ mW2,
    const float* __restrict__ pW1, const float* __restrict__ pb1,
    const float* __restrict__ pW2, const float* __restrict__ pb2,
    const float* __restrict__ pW3, const float* __restrict__ pb3,
    unsigned* __restrict__ ws)
{
    const int t = threadIdx.x;           // 64 threads
    float* wf = (float*)ws;

    if (t < 8)  ws[OFF_MW0 + t] = h2bits(pk(mW0[t*2], mW0[t*2+1]));
    if (t < 32) { int o = t >> 2, k = t & 3;
        ws[OFF_MW1 + t] = h2bits(pk(mW1[o*8 + 2*k], mW1[o*8 + 2*k + 1])); }
    if (t < 16) { int o = t >> 2, k = t & 3;
        ws[OFF_MW2 + t] = h2bits(pk(mW2[o*8 + 2*k], mW2[o*8 + 2*k + 1])); }
    if (t < 16) ws[OFF_PW1F + t] = h2bits(pk(TL2E*pW1[t*2], TL2E*pW1[t*2+1]));
    { int v = t >> 5, q = (t >> 2) & 7, k = t & 3;
      ws[OFF_PW2F + t] = h2bits(pk(TL2E*pW2[v*64 + q*8 + 2*k],
                                   TL2E*pW2[v*64 + q*8 + 2*k + 1])); }
    if (t < 8) { int v = t >> 2, k = t & 3;
        ws[OFF_PW3F + t] = h2bits(pk(-L2E*pW3[v*8 + 2*k], -L2E*pW3[v*8 + 2*k + 1])); }
    { int v = t >> 5, p = (t >> 2) & 7, k = t & 3;
      ws[OFF_PW2T + t] = h2bits(pk(pW2[v*64 + (2*k)*8 + p],
                                   pW2[v*64 + (2*k+1)*8 + p])); }
    if (t < 16) { int v = t >> 3, i = (t >> 2) & 1, k = t & 3;
        ws[OFF_PW1T + t] = h2bits(pk(pW1[v*16 + (2*k)*2 + i],
                                     pW1[v*16 + (2*k+1)*2 + i])); }
    if (t < 16) wf[FOFF_PB1 + t] = TL2E * pb1[t];
    if (t < 16) wf[FOFF_PB2 + t] = TL2E * pb2[t];
    if (t < 2)  wf[FOFF_PB3 + t] = -L2E * pb3[t];
}

// tanh from pre-scaled z (z = 2*log2(e)*x): tanh = 1 - 2/(2^z + 1).
// e clamped <=1e8 so the 4-way rcp-batch product stays < 1e33.
static __device__ __forceinline__ void tanh8s(float* d) {
#pragma unroll
    for (int i = 0; i < 8; ++i) {
        float e = __builtin_amdgcn_exp2f(d[i]);
        d[i] = fminf(e, 1e8f) + 1.f;
    }
#pragma unroll
    for (int g = 0; g < 2; ++g) {
        float* q = d + 4*g;
        float ab = q[0]*q[1], cd = q[2]*q[3];
        float inv = __builtin_amdgcn_rcpf(ab*cd);
        float s = cd*inv, t = ab*inv;
        float r0 = q[1]*s, r1 = q[0]*s, r2 = q[3]*t, r3 = q[2]*t;
        q[0] = fmaf(r0, -2.f, 1.f);
        q[1] = fmaf(r1, -2.f, 1.f);
        q[2] = fmaf(r2, -2.f, 1.f);
        q[3] = fmaf(r3, -2.f, 1.f);
    }
}
// elu(x) = max(x, min(e^x - 1, 0)); NaN-free, branchless.
static __device__ __forceinline__ float elus(float z) {
    float e = __builtin_amdgcn_exp2f(z * L2E);
    return fmaxf(z, fminf(e - 1.f, 0.f));
}

// Layer-lockstep: both points advance together (pt = innermost loop) so each
// weight word is s_loaded ONCE with a short live range, and every dependent
// chain has an independent twin for ILP.
__global__ __launch_bounds__(256) void odefunc_kernel(
    const float* __restrict__ x,
    const unsigned* __restrict__ W,
    const float* __restrict__ mb0, const float* __restrict__ mb1,
    const float* __restrict__ mb2, const float* __restrict__ pW3,
    float* __restrict__ out)
{
    const int tid = blockIdx.x * blockDim.x + threadIdx.x;
    const int b0  = tid * 2;                 // 2 points per thread, lockstep
    const float* Wf = (const float*)W;

    const float4 xv = *reinterpret_cast<const float4*>(x + b0 * 2);
    h2 xh[2] = { pk(xv.x, xv.y), pk(xv.z, xv.w) };

    // ---- m-branch: 2 -> 8 -> 8 -> 4, ELU ----
    float z[2][8], h[2][8];
    h2 hp[2][4];
#pragma unroll
    for (int o = 0; o < 8; ++o) {
        h2 w = bits2h(W[OFF_MW0 + o]);
#pragma unroll
        for (int pt = 0; pt < 2; ++pt) z[pt][o] = fdot2(xh[pt], w, mb0[o]);
    }
#pragma unroll
    for (int o = 0; o < 8; ++o)
#pragma unroll
        for (int pt = 0; pt < 2; ++pt) h[pt][o] = elus(z[pt][o]);
#pragma unroll
    for (int k = 0; k < 4; ++k)
#pragma unroll
        for (int pt = 0; pt < 2; ++pt) hp[pt][k] = pk(h[pt][2*k], h[pt][2*k+1]);

#pragma unroll
    for (int o = 0; o < 8; ++o) {
        float a[2] = { mb1[o], mb1[o] };
#pragma unroll
        for (int k = 0; k < 4; ++k) {
            h2 w = bits2h(W[OFF_MW1 + o*4 + k]);
#pragma unroll
            for (int pt = 0; pt < 2; ++pt) a[pt] = fdot2(hp[pt][k], w, a[pt]);
        }
        z[0][o] = a[0]; z[1][o] = a[1];
    }
#pragma unroll
    for (int o = 0; o < 8; ++o)
#pragma unroll
        for (int pt = 0; pt < 2; ++pt) h[pt][o] = elus(z[pt][o]);
#pragma unroll
    for (int k = 0; k < 4; ++k)
#pragma unroll
        for (int pt = 0; pt < 2; ++pt) hp[pt][k] = pk(h[pt][2*k], h[pt][2*k+1]);

    float bm[2][4];
#pragma unroll
    for (int o = 0; o < 4; ++o) {
        float a[2] = { mb2[o], mb2[o] };
#pragma unroll
        for (int k = 0; k < 4; ++k) {
            h2 w = bits2h(W[OFF_MW2 + o*4 + k]);
#pragma unroll
            for (int pt = 0; pt < 2; ++pt) a[pt] = fdot2(hp[pt][k], w, a[pt]);
        }
        bm[0][o] = a[0]; bm[1][o] = a[1];
    }
    float m2[2], mag0[2], mag3[2];
#pragma unroll
    for (int pt = 0; pt < 2; ++pt) {
        m2[pt]   = bm[pt][0]*bm[pt][1] + bm[pt][2]*bm[pt][3];
        mag0[pt] = bm[pt][0]*bm[pt][0] + bm[pt][2]*bm[pt][2];
        mag3[pt] = bm[pt][1]*bm[pt][1] + bm[pt][3]*bm[pt][3];
    }

    // ---- p-branch: NV nets, fwd + analytic input-grad bwd ----
    float g0[2] = {0.f, 0.f}, g1[2] = {0.f, 0.f};
#pragma unroll
    for (int v = 0; v < NV; ++v) {
        float f1[2][8], f2[2][8];
        h2 f1p[2][4], f2p[2][4];
#pragma unroll
        for (int o = 0; o < 8; ++o) {
            h2 w = bits2h(W[OFF_PW1F + v*8 + o]);
            float b = Wf[FOFF_PB1 + v*8 + o];
#pragma unroll
            for (int pt = 0; pt < 2; ++pt) f1[pt][o] = fdot2(xh[pt], w, b);
        }
        tanh8s(f1[0]); tanh8s(f1[1]);
#pragma unroll
        for (int k = 0; k < 4; ++k)
#pragma unroll
            for (int pt = 0; pt < 2; ++pt) f1p[pt][k] = pk(f1[pt][2*k], f1[pt][2*k+1]);

#pragma unroll
        for (int q = 0; q < 8; ++q) {
            float b = Wf[FOFF_PB2 + v*8 + q];
            float a[2] = { b, b };
#pragma unroll
            for (int k = 0; k < 4; ++k) {
                h2 w = bits2h(W[OFF_PW2F + v*32 + q*4 + k]);
#pragma unroll
                for (int pt = 0; pt < 2; ++pt) a[pt] = fdot2(f1p[pt][k], w, a[pt]);
            }
            f2[0][q] = a[0]; f2[1][q] = a[1];
        }
        tanh8s(f2[0]); tanh8s(f2[1]);
#pragma unroll
        for (int k = 0; k < 4; ++k)
#pragma unroll
            for (int pt = 0; pt < 2; ++pt) f2p[pt][k] = pk(f2[pt][2*k], f2[pt][2*k+1]);

        float z3b = Wf[FOFF_PB3 + v];            // pre-scaled by -log2(e)
        float z3[2] = { z3b, z3b };
#pragma unroll
        for (int k = 0; k < 4; ++k) {
            h2 w = bits2h(W[OFF_PW3F + v*4 + k]);
#pragma unroll
            for (int pt = 0; pt < 2; ++pt) z3[pt] = fdot2(f2p[pt][k], w, z3[pt]);
        }
        float ss[2];
#pragma unroll
        for (int pt = 0; pt < 2; ++pt) {
            const float e1 = __builtin_amdgcn_exp2f(z3[pt]);       // e^{-raw}
            const float f3 = __builtin_amdgcn_rcpf(e1 + 1.f);
            const float e2 = __builtin_amdgcn_exp2f(f3 * (-L2E));  // f3 in (0,1)
            const float s  = __builtin_amdgcn_rcpf(e2 + 1.f);
            ss[pt] = s * (1.f - s);
        }

        // gq = W3 .* (1 - f2^2), packed f16 (ss folded at the end)
        h2 gqp[2][4];
#pragma unroll
        for (int k = 0; k < 4; ++k) {
            float wa = pW3[v*8 + 2*k], wb = pW3[v*8 + 2*k + 1];
#pragma unroll
            for (int pt = 0; pt < 2; ++pt) {
                float a = wa * fmaf(-f2[pt][2*k],   f2[pt][2*k],   1.f);
                float b = wb * fmaf(-f2[pt][2*k+1], f2[pt][2*k+1], 1.f);
                gqp[pt][k] = pk(a, b);
            }
        }
        // gp[p] = (sum_q gq[q] W2[q][p]) * (1 - f1[p]^2)
        float gp[2][8];
#pragma unroll
        for (int p = 0; p < 8; ++p) {
            float a[2] = { 0.f, 0.f };
#pragma unroll
            for (int k = 0; k < 4; ++k) {
                h2 w = bits2h(W[OFF_PW2T + v*32 + p*4 + k]);
#pragma unroll
                for (int pt = 0; pt < 2; ++pt) a[pt] = fdot2(gqp[pt][k], w, a[pt]);
            }
#pragma unroll
            for (int pt = 0; pt < 2; ++pt)
                gp[pt][p] = a[pt] * fmaf(-f1[pt][p], f1[pt][p], 1.f);
        }
        h2 gpp[2][4];
#pragma unroll
        for (int k = 0; k < 4; ++k)
#pragma unroll
            for (int pt = 0; pt < 2; ++pt) gpp[pt][k] = pk(gp[pt][2*k], gp[pt][2*k+1]);

        float gi0[2] = {0.f, 0.f}, gi1[2] = {0.f, 0.f};
#pragma unroll
        for (int k = 0; k < 4; ++k) {
            h2 w0 = bits2h(W[OFF_PW1T + v*8 + k]);
            h2 w1 = bits2h(W[OFF_PW1T + v*8 + 4 + k]);
#pragma unroll
            for (int pt = 0; pt < 2; ++pt) {
                gi0[pt] = fdot2(gpp[pt][k], w0, gi0[pt]);
                gi1[pt] = fdot2(gpp[pt][k], w1, gi1[pt]);
            }
        }
#pragma unroll
        for (int pt = 0; pt < 2; ++pt) {
            g0[pt] = fmaf(ss[pt], gi0[pt], g0[pt]);
            g1[pt] = fmaf(ss[pt], gi1[pt], g1[pt]);
        }
    }

    float r[2][2];
#pragma unroll
    for (int pt = 0; pt < 2; ++pt) {
        const float a = g0[pt] * 0.5f, b = g1[pt] * 0.5f;  // mean over NV=2
        r[pt][0] = mag0[pt]*a + m2[pt]*b;
        r[pt][1] = m2[pt]*a + mag3[pt]*b;
    }
    *reinterpret_cast<float4*>(out + b0 * 2) = make_float4(r[0][0], r[0][1], r[1][0], r[1][1]);
}

extern "C" void kernel_launch(void* const* d_in, const int* in_sizes, int n_in,
                              void* d_out, int out_size, void* d_ws, size_t ws_size,
                              hipStream_t stream) {
    // order: t, x, mW0, mb0, mW1, mb1, mW2, mb2, pW1, pb1, pW2, pb2, pW3, pb3
    const float* x   = (const float*)d_in[1];
    const float* mW0 = (const float*)d_in[2];
    const float* mb0 = (const float*)d_in[3];
    const float* mW1 = (const float*)d_in[4];
    const float* mb1 = (const float*)d_in[5];
    const float* mW2 = (const float*)d_in[6];
    const float* mb2 = (const float*)d_in[7];
    const float* pW1 = (const float*)d_in[8];
    const float* pb1 = (const float*)d_in[9];
    const float* pW2 = (const float*)d_in[10];
    const float* pb2 = (const float*)d_in[11];
    const float* pW3 = (const float*)d_in[12];
    const float* pb3 = (const float*)d_in[13];
    unsigned* ws = (unsigned*)d_ws;
    float* out = (float*)d_out;

    prep_kernel<<<1, 64, 0, stream>>>(mW0, mW1, mW2, pW1, pb1, pW2, pb2, pW3, pb3, ws);

    const int threads = 256;
    const int blocks  = NB / (threads * 2);   // 4096 blocks
    odefunc_kernel<<<blocks, threads, 0, stream>>>(x, ws, mb0, mb1, mb2, pW3, out);
}

// Round 7
// 136.613 us; speedup vs baseline: 1.4367x; 1.0053x over previous
//
#include <hip/hip_runtime.h>

#define NB 2097152
#define HM 8
#define HP 8
#define NV 2

// NOTE: clang's amdgcn builtins (cvt_pkrtz, fdot2) use __fp16 vectors.
typedef __fp16 h2 __attribute__((ext_vector_type(2)));

// Packed-weight workspace layout (32-bit words; h2 pairs unless noted f32):
#define OFF_MW0   0     // mW0p[8]        pairs over i (unscaled)
#define OFF_MW1   8     // mW1p[8][4]     pairs over i
#define OFF_MW2   40    // mW2p[4][4]     pairs over i
#define OFF_PW1F  56    // pW1f[v][8]     pairs over i, scaled 2*log2(e)
#define OFF_PW2F  72    // pW2f[v][8][4]  pairs over p, scaled 2*log2(e)
#define OFF_PW3F  136   // pW3f[v][4]     pairs over p, scaled -log2(e)
#define OFF_PW2T  144   // pW2T[v][8][4]  pairs over q (transposed, unscaled)
#define OFF_PW1T  208   // pW1T[v][2][4]  pairs over p (transposed, unscaled)
#define FOFF_PB1  224   // f32 2*log2(e)*pb1 [16]
#define FOFF_PB2  240   // f32 2*log2(e)*pb2 [16]
#define FOFF_PB3  256   // f32 -log2(e)*pb3 [2]

#define L2E  1.4426950408889634f
#define TL2E 2.8853901635333640f   // 2*log2(e)

static __device__ __forceinline__ h2 pk(float a, float b) {
    return __builtin_amdgcn_cvt_pkrtz(a, b);
}
static __device__ __forceinline__ float fdot2(h2 a, h2 b, float c) {
    return __builtin_amdgcn_fdot2(a, b, c, false);   // v_dot2_f32_f16
}
static __device__ __forceinline__ unsigned h2bits(h2 v) {
    union { h2 h; unsigned u; } c; c.h = v; return c.u;
}
static __device__ __forceinline__ h2 bits2h(unsigned u) {
    union { h2 h; unsigned u; } c; c.u = u; return c.h;
}

// ---------------- prep: pack/scale weights into ws ----------------
__global__ void prep_kernel(
    const float* __restrict__ mW0, const float* __restrict__ mW1,
    const float* __restrict__ mW2,
    const float* __restrict__ pW1, const float* __restrict__ pb1,
    const float* __restrict__ pW2, const float* __restrict__ pb2,
    const float* __restrict__ pW3, const float* __restrict__ pb3,
    unsigned* __restrict__ ws)
{
    const int t = threadIdx.x;           // 64 threads
    float* wf = (float*)ws;

    if (t < 8)  ws[OFF_MW0 + t] = h2bits(pk(mW0[t*2], mW0[t*2+1]));
    if (t < 32) { int o = t >> 2, k = t & 3;
        ws[OFF_MW1 + t] = h2bits(pk(mW1[o*8 + 2*k], mW1[o*8 + 2*k + 1])); }
    if (t < 16) { int o = t >> 2, k = t & 3;
        ws[OFF_MW2 + t] = h2bits(pk(mW2[o*8 + 2*k], mW2[o*8 + 2*k + 1])); }
    if (t < 16) ws[OFF_PW1F + t] = h2bits(pk(TL2E*pW1[t*2], TL2E*pW1[t*2+1]));
    { int v = t >> 5, q = (t >> 2) & 7, k = t & 3;
      ws[OFF_PW2F + t] = h2bits(pk(TL2E*pW2[v*64 + q*8 + 2*k],
                                   TL2E*pW2[v*64 + q*8 + 2*k + 1])); }
    if (t < 8) { int v = t >> 2, k = t & 3;
        ws[OFF_PW3F + t] = h2bits(pk(-L2E*pW3[v*8 + 2*k], -L2E*pW3[v*8 + 2*k + 1])); }
    { int v = t >> 5, p = (t >> 2) & 7, k = t & 3;
      ws[OFF_PW2T + t] = h2bits(pk(pW2[v*64 + (2*k)*8 + p],
                                   pW2[v*64 + (2*k+1)*8 + p])); }
    if (t < 16) { int v = t >> 3, i = (t >> 2) & 1, k = t & 3;
        ws[OFF_PW1T + t] = h2bits(pk(pW1[v*16 + (2*k)*2 + i],
                                     pW1[v*16 + (2*k+1)*2 + i])); }
    if (t < 16) wf[FOFF_PB1 + t] = TL2E * pb1[t];
    if (t < 16) wf[FOFF_PB2 + t] = TL2E * pb2[t];
    if (t < 2)  wf[FOFF_PB3 + t] = -L2E * pb3[t];
}

// tanh from pre-scaled z (z = 2*log2(e)*x): tanh = 1 - 2/(2^z + 1).
// e clamped <=1e8 so the 4-way rcp-batch product stays < 1e33.
static __device__ __forceinline__ void tanh8s(float* d) {
#pragma unroll
    for (int i = 0; i < 8; ++i) {
        float e = __builtin_amdgcn_exp2f(d[i]);
        d[i] = fminf(e, 1e8f) + 1.f;
    }
#pragma unroll
    for (int g = 0; g < 2; ++g) {
        float* q = d + 4*g;
        float ab = q[0]*q[1], cd = q[2]*q[3];
        float inv = __builtin_amdgcn_rcpf(ab*cd);
        float s = cd*inv, t = ab*inv;
        float r0 = q[1]*s, r1 = q[0]*s, r2 = q[3]*t, r3 = q[2]*t;
        q[0] = fmaf(r0, -2.f, 1.f);
        q[1] = fmaf(r1, -2.f, 1.f);
        q[2] = fmaf(r2, -2.f, 1.f);
        q[3] = fmaf(r3, -2.f, 1.f);
    }
}
// elu(x) = max(x, min(e^x - 1, 0)); NaN-free, branchless.
static __device__ __forceinline__ float elus(float z) {
    float e = __builtin_amdgcn_exp2f(z * L2E);
    return fmaxf(z, fminf(e - 1.f, 0.f));
}
// Outer sigmoid of the double-sigmoid: input u = sigma(z3) is ALWAYS in (0,1),
// so a cubic fit suffices (max err ~3e-5 on [0,1]) -> saves exp+rcp per net.
static __device__ __forceinline__ float sig01(float u) {
    return fmaf(u, fmaf(u, fmaf(u, -0.01566459f, -0.0040905f), 0.2508141f), 0.5f);
}

// Layer-lockstep: both points advance together (pt = innermost loop) so each
// weight word is s_loaded ONCE, and every chain has an independent twin.
// __launch_bounds__(256,4): cap 128 VGPR — R6's 32-VGPR allocation starved the
// f32 state (f1/f2 = 32 live floats) into pack/unpack shuffling.
__global__ __launch_bounds__(256, 4) void odefunc_kernel(
    const float* __restrict__ x,
    const unsigned* __restrict__ W,
    const float* __restrict__ mb0, const float* __restrict__ mb1,
    const float* __restrict__ mb2, const float* __restrict__ pW3,
    float* __restrict__ out)
{
    const int tid = blockIdx.x * blockDim.x + threadIdx.x;
    const int b0  = tid * 2;                 // 2 points per thread, lockstep
    const float* Wf = (const float*)W;

    const float4 xv = *reinterpret_cast<const float4*>(x + b0 * 2);
    h2 xh[2] = { pk(xv.x, xv.y), pk(xv.z, xv.w) };

    // ---- m-branch: 2 -> 8 -> 8 -> 4, ELU ----
    float z[2][8], h[2][8];
    h2 hp[2][4];
#pragma unroll
    for (int o = 0; o < 8; ++o) {
        h2 w = bits2h(W[OFF_MW0 + o]);
#pragma unroll
        for (int pt = 0; pt < 2; ++pt) z[pt][o] = fdot2(xh[pt], w, mb0[o]);
    }
#pragma unroll
    for (int o = 0; o < 8; ++o)
#pragma unroll
        for (int pt = 0; pt < 2; ++pt) h[pt][o] = elus(z[pt][o]);
#pragma unroll
    for (int k = 0; k < 4; ++k)
#pragma unroll
        for (int pt = 0; pt < 2; ++pt) hp[pt][k] = pk(h[pt][2*k], h[pt][2*k+1]);

#pragma unroll
    for (int o = 0; o < 8; ++o) {
        float a[2] = { mb1[o], mb1[o] };
#pragma unroll
        for (int k = 0; k < 4; ++k) {
            h2 w = bits2h(W[OFF_MW1 + o*4 + k]);
#pragma unroll
            for (int pt = 0; pt < 2; ++pt) a[pt] = fdot2(hp[pt][k], w, a[pt]);
        }
        z[0][o] = a[0]; z[1][o] = a[1];
    }
#pragma unroll
    for (int o = 0; o < 8; ++o)
#pragma unroll
        for (int pt = 0; pt < 2; ++pt) h[pt][o] = elus(z[pt][o]);
#pragma unroll
    for (int k = 0; k < 4; ++k)
#pragma unroll
        for (int pt = 0; pt < 2; ++pt) hp[pt][k] = pk(h[pt][2*k], h[pt][2*k+1]);

    float bm[2][4];
#pragma unroll
    for (int o = 0; o < 4; ++o) {
        float a[2] = { mb2[o], mb2[o] };
#pragma unroll
        for (int k = 0; k < 4; ++k) {
            h2 w = bits2h(W[OFF_MW2 + o*4 + k]);
#pragma unroll
            for (int pt = 0; pt < 2; ++pt) a[pt] = fdot2(hp[pt][k], w, a[pt]);
        }
        bm[0][o] = a[0]; bm[1][o] = a[1];
    }
    float m2[2], mag0[2], mag3[2];
#pragma unroll
    for (int pt = 0; pt < 2; ++pt) {
        m2[pt]   = bm[pt][0]*bm[pt][1] + bm[pt][2]*bm[pt][3];
        mag0[pt] = bm[pt][0]*bm[pt][0] + bm[pt][2]*bm[pt][2];
        mag3[pt] = bm[pt][1]*bm[pt][1] + bm[pt][3]*bm[pt][3];
    }

    // ---- p-branch: NV nets, fwd + analytic input-grad bwd ----
    float g0[2] = {0.f, 0.f}, g1[2] = {0.f, 0.f};
#pragma unroll
    for (int v = 0; v < NV; ++v) {
        float f1[2][8], f2[2][8];
        h2 f1p[2][4], f2p[2][4];
#pragma unroll
        for (int o = 0; o < 8; ++o) {
            h2 w = bits2h(W[OFF_PW1F + v*8 + o]);
            float b = Wf[FOFF_PB1 + v*8 + o];
#pragma unroll
            for (int pt = 0; pt < 2; ++pt) f1[pt][o] = fdot2(xh[pt], w, b);
        }
        tanh8s(f1[0]); tanh8s(f1[1]);
#pragma unroll
        for (int k = 0; k < 4; ++k)
#pragma unroll
            for (int pt = 0; pt < 2; ++pt) f1p[pt][k] = pk(f1[pt][2*k], f1[pt][2*k+1]);

#pragma unroll
        for (int q = 0; q < 8; ++q) {
            float b = Wf[FOFF_PB2 + v*8 + q];
            float a[2] = { b, b };
#pragma unroll
            for (int k = 0; k < 4; ++k) {
                h2 w = bits2h(W[OFF_PW2F + v*32 + q*4 + k]);
#pragma unroll
                for (int pt = 0; pt < 2; ++pt) a[pt] = fdot2(f1p[pt][k], w, a[pt]);
            }
            f2[0][q] = a[0]; f2[1][q] = a[1];
        }
        tanh8s(f2[0]); tanh8s(f2[1]);
#pragma unroll
        for (int k = 0; k < 4; ++k)
#pragma unroll
            for (int pt = 0; pt < 2; ++pt) f2p[pt][k] = pk(f2[pt][2*k], f2[pt][2*k+1]);

        float z3b = Wf[FOFF_PB3 + v];            // pre-scaled by -log2(e)
        float z3[2] = { z3b, z3b };
#pragma unroll
        for (int k = 0; k < 4; ++k) {
            h2 w = bits2h(W[OFF_PW3F + v*4 + k]);
#pragma unroll
            for (int pt = 0; pt < 2; ++pt) z3[pt] = fdot2(f2p[pt][k], w, z3[pt]);
        }
        float ss[2];
#pragma unroll
        for (int pt = 0; pt < 2; ++pt) {
            const float e1 = __builtin_amdgcn_exp2f(z3[pt]);       // 2^{-L2E-scaled}
            const float f3 = __builtin_amdgcn_rcpf(e1 + 1.f);      // inner sigmoid
            const float s  = sig01(f3);                            // outer: cubic
            ss[pt] = s * (1.f - s);
        }

        // gq = W3 .* (1 - f2^2), packed f16 (ss folded at the end)
        h2 gqp[2][4];
#pragma unroll
        for (int k = 0; k < 4; ++k) {
            float wa = pW3[v*8 + 2*k], wb = pW3[v*8 + 2*k + 1];
#pragma unroll
            for (int pt = 0; pt < 2; ++pt) {
                float a = wa * fmaf(-f2[pt][2*k],   f2[pt][2*k],   1.f);
                float b = wb * fmaf(-f2[pt][2*k+1], f2[pt][2*k+1], 1.f);
                gqp[pt][k] = pk(a, b);
            }
        }
        // gp[p] = (sum_q gq[q] W2[q][p]) * (1 - f1[p]^2)
        float gp[2][8];
#pragma unroll
        for (int p = 0; p < 8; ++p) {
            float a[2] = { 0.f, 0.f };
#pragma unroll
            for (int k = 0; k < 4; ++k) {
                h2 w = bits2h(W[OFF_PW2T + v*32 + p*4 + k]);
#pragma unroll
                for (int pt = 0; pt < 2; ++pt) a[pt] = fdot2(gqp[pt][k], w, a[pt]);
            }
#pragma unroll
            for (int pt = 0; pt < 2; ++pt)
                gp[pt][p] = a[pt] * fmaf(-f1[pt][p], f1[pt][p], 1.f);
        }
        h2 gpp[2][4];
#pragma unroll
        for (int k = 0; k < 4; ++k)
#pragma unroll
            for (int pt = 0; pt < 2; ++pt) gpp[pt][k] = pk(gp[pt][2*k], gp[pt][2*k+1]);

        float gi0[2] = {0.f, 0.f}, gi1[2] = {0.f, 0.f};
#pragma unroll
        for (int k = 0; k < 4; ++k) {
            h2 w0 = bits2h(W[OFF_PW1T + v*8 + k]);
            h2 w1 = bits2h(W[OFF_PW1T + v*8 + 4 + k]);
#pragma unroll
            for (int pt = 0; pt < 2; ++pt) {
                gi0[pt] = fdot2(gpp[pt][k], w0, gi0[pt]);
                gi1[pt] = fdot2(gpp[pt][k], w1, gi1[pt]);
            }
        }
#pragma unroll
        for (int pt = 0; pt < 2; ++pt) {
            g0[pt] = fmaf(ss[pt], gi0[pt], g0[pt]);
            g1[pt] = fmaf(ss[pt], gi1[pt], g1[pt]);
        }
    }

    float r[2][2];
#pragma unroll
    for (int pt = 0; pt < 2; ++pt) {
        const float a = g0[pt] * 0.5f, b = g1[pt] * 0.5f;  // mean over NV=2
        r[pt][0] = mag0[pt]*a + m2[pt]*b;
        r[pt][1] = m2[pt]*a + mag3[pt]*b;
    }
    *reinterpret_cast<float4*>(out + b0 * 2) = make_float4(r[0][0], r[0][1], r[1][0], r[1][1]);
}

extern "C" void kernel_launch(void* const* d_in, const int* in_sizes, int n_in,
                              void* d_out, int out_size, void* d_ws, size_t ws_size,
                              hipStream_t stream) {
    // order: t, x, mW0, mb0, mW1, mb1, mW2, mb2, pW1, pb1, pW2, pb2, pW3, pb3
    const float* x   = (const float*)d_in[1];
    const float* mW0 = (const float*)d_in[2];
    const float* mb0 = (const float*)d_in[3];
    const float* mW1 = (const float*)d_in[4];
    const float* mb1 = (const float*)d_in[5];
    const float* mW2 = (const float*)d_in[6];
    const float* mb2 = (const float*)d_in[7];
    const float* pW1 = (const float*)d_in[8];
    const float* pb1 = (const float*)d_in[9];
    const float* pW2 = (const float*)d_in[10];
    const float* pb2 = (const float*)d_in[11];
    const float* pW3 = (const float*)d_in[12];
    const float* pb3 = (const float*)d_in[13];
    unsigned* ws = (unsigned*)d_ws;
    float* out = (float*)d_out;

    prep_kernel<<<1, 64, 0, stream>>>(mW0, mW1, mW2, pW1, pb1, pW2, pb2, pW3, pb3, ws);

    const int threads = 256;
    const int blocks  = NB / (threads * 2);   // 4096 blocks
    odefunc_kernel<<<blocks, threads, 0, stream>>>(x, ws, mb0, mb1, mb2, pW3, out);
}

// Round 8
// 135.262 us; speedup vs baseline: 1.4510x; 1.0100x over previous
//
#include <hip/hip_runtime.h>

#define NB 2097152
#define HM 8
#define HP 8
#define NV 2

// NOTE: clang's amdgcn builtins (cvt_pkrtz, fdot2) use __fp16 vectors.
typedef __fp16 h2 __attribute__((ext_vector_type(2)));

// Packed-weight workspace layout (32-bit words; h2 pairs unless noted f32):
#define OFF_MW0   0     // mW0p[8]        pairs over i (unscaled)
#define OFF_MW1   8     // mW1p[8][4]     pairs over i
#define OFF_MW2   40    // mW2p[4][4]     pairs over i
#define OFF_PW1F  56    // pW1f[v][8]     pairs over i, scaled 2*log2(e)
#define OFF_PW2F  72    // pW2f[v][8][4]  pairs over p, scaled 2*log2(e)
#define OFF_PW3F  136   // pW3f[v][4]     pairs over p, scaled -log2(e)
#define OFF_PW2T  144   // V2T[v][8][4]   pairs over q, = W3[q]*W2[q][p] (folded!)
#define OFF_PW1T  208   // pW1T[v][2][4]  pairs over p (transposed, unscaled)
#define FOFF_PB1  224   // f32 2*log2(e)*pb1 [16]
#define FOFF_PB2  240   // f32 2*log2(e)*pb2 [16]
#define FOFF_PB3  256   // f32 -log2(e)*pb3 [2]

#define L2E  1.4426950408889634f
#define TL2E 2.8853901635333640f   // 2*log2(e)

static __device__ __forceinline__ h2 pk(float a, float b) {
    return __builtin_amdgcn_cvt_pkrtz(a, b);
}
static __device__ __forceinline__ float fdot2(h2 a, h2 b, float c) {
    return __builtin_amdgcn_fdot2(a, b, c, false);   // v_dot2_f32_f16
}
static __device__ __forceinline__ unsigned h2bits(h2 v) {
    union { h2 h; unsigned u; } c; c.h = v; return c.u;
}
static __device__ __forceinline__ h2 bits2h(unsigned u) {
    union { h2 h; unsigned u; } c; c.u = u; return c.h;
}

// ---------------- prep: pack/scale weights into ws ----------------
__global__ void prep_kernel(
    const float* __restrict__ mW0, const float* __restrict__ mW1,
    const float* __restrict__ mW2,
    const float* __restrict__ pW1, const float* __restrict__ pb1,
    const float* __restrict__ pW2, const float* __restrict__ pb2,
    const float* __restrict__ pW3, const float* __restrict__ pb3,
    unsigned* __restrict__ ws)
{
    const int t = threadIdx.x;           // 64 threads
    float* wf = (float*)ws;

    if (t < 8)  ws[OFF_MW0 + t] = h2bits(pk(mW0[t*2], mW0[t*2+1]));
    if (t < 32) { int o = t >> 2, k = t & 3;
        ws[OFF_MW1 + t] = h2bits(pk(mW1[o*8 + 2*k], mW1[o*8 + 2*k + 1])); }
    if (t < 16) { int o = t >> 2, k = t & 3;
        ws[OFF_MW2 + t] = h2bits(pk(mW2[o*8 + 2*k], mW2[o*8 + 2*k + 1])); }
    if (t < 16) ws[OFF_PW1F + t] = h2bits(pk(TL2E*pW1[t*2], TL2E*pW1[t*2+1]));
    { int v = t >> 5, q = (t >> 2) & 7, k = t & 3;
      ws[OFF_PW2F + t] = h2bits(pk(TL2E*pW2[v*64 + q*8 + 2*k],
                                   TL2E*pW2[v*64 + q*8 + 2*k + 1])); }
    if (t < 8) { int v = t >> 2, k = t & 3;
        ws[OFF_PW3F + t] = h2bits(pk(-L2E*pW3[v*8 + 2*k], -L2E*pW3[v*8 + 2*k + 1])); }
    { // V2T: transposed W2 with W3 row-factor folded in: pair over q of W3[q]*W2[q][p]
      int v = t >> 5, p = (t >> 2) & 7, k = t & 3;
      ws[OFF_PW2T + t] = h2bits(pk(pW3[v*8 + 2*k]     * pW2[v*64 + (2*k)*8 + p],
                                   pW3[v*8 + 2*k + 1] * pW2[v*64 + (2*k+1)*8 + p])); }
    if (t < 16) { int v = t >> 3, i = (t >> 2) & 1, k = t & 3;
        ws[OFF_PW1T + t] = h2bits(pk(pW1[v*16 + (2*k)*2 + i],
                                     pW1[v*16 + (2*k+1)*2 + i])); }
    if (t < 16) wf[FOFF_PB1 + t] = TL2E * pb1[t];
    if (t < 16) wf[FOFF_PB2 + t] = TL2E * pb2[t];
    if (t < 2)  wf[FOFF_PB3 + t] = -L2E * pb3[t];
}

// tanh from pre-scaled z (z = 2*log2(e)*x): tanh = 1 - 2/(2^z + 1).
// 4 ops/value: exp2, add, rcp, fma. Overflow-clean: e=inf -> rcp=0 -> +1 exact.
static __device__ __forceinline__ void tanh8s(float* d) {
#pragma unroll
    for (int i = 0; i < 8; ++i) {
        float e = __builtin_amdgcn_exp2f(d[i]);
        float r = __builtin_amdgcn_rcpf(e + 1.f);
        d[i] = fmaf(r, -2.f, 1.f);
    }
}
// elu(z) = med3(z, e^z - 1, 0): e^z-1 >= z for z>0 -> median z; z < e^z-1 < 0
// for z<0 -> median e^z-1. 4 ops: mul, exp2, add, med3. NaN-free.
static __device__ __forceinline__ float elus(float z) {
    float e = __builtin_amdgcn_exp2f(z * L2E);
    return __builtin_amdgcn_fmed3f(z, e - 1.f, 0.f);
}
// Outer sigmoid of the double-sigmoid: input u = sigma(z3) is in (0,1);
// cubic fit (max err ~3e-5 on [0,1]).
static __device__ __forceinline__ float sig01(float u) {
    return fmaf(u, fmaf(u, fmaf(u, -0.01566459f, -0.0040905f), 0.2508141f), 0.5f);
}

// Layer-lockstep: both points advance together; each weight s_loaded once.
__global__ __launch_bounds__(256, 4) void odefunc_kernel(
    const float* __restrict__ x,
    const unsigned* __restrict__ W,
    const float* __restrict__ mb0, const float* __restrict__ mb1,
    const float* __restrict__ mb2,
    float* __restrict__ out)
{
    const int tid = blockIdx.x * blockDim.x + threadIdx.x;
    const int b0  = tid * 2;                 // 2 points per thread, lockstep
    const float* Wf = (const float*)W;

    const float4 xv = *reinterpret_cast<const float4*>(x + b0 * 2);
    h2 xh[2] = { pk(xv.x, xv.y), pk(xv.z, xv.w) };

    // ---- m-branch: 2 -> 8 -> 8 -> 4, ELU ----
    float z[2][8], h[2][8];
    h2 hp[2][4];
#pragma unroll
    for (int o = 0; o < 8; ++o) {
        h2 w = bits2h(W[OFF_MW0 + o]);
#pragma unroll
        for (int pt = 0; pt < 2; ++pt) z[pt][o] = fdot2(xh[pt], w, mb0[o]);
    }
#pragma unroll
    for (int o = 0; o < 8; ++o)
#pragma unroll
        for (int pt = 0; pt < 2; ++pt) h[pt][o] = elus(z[pt][o]);
#pragma unroll
    for (int k = 0; k < 4; ++k)
#pragma unroll
        for (int pt = 0; pt < 2; ++pt) hp[pt][k] = pk(h[pt][2*k], h[pt][2*k+1]);

#pragma unroll
    for (int o = 0; o < 8; ++o) {
        float a[2] = { mb1[o], mb1[o] };
#pragma unroll
        for (int k = 0; k < 4; ++k) {
            h2 w = bits2h(W[OFF_MW1 + o*4 + k]);
#pragma unroll
            for (int pt = 0; pt < 2; ++pt) a[pt] = fdot2(hp[pt][k], w, a[pt]);
        }
        z[0][o] = a[0]; z[1][o] = a[1];
    }
#pragma unroll
    for (int o = 0; o < 8; ++o)
#pragma unroll
        for (int pt = 0; pt < 2; ++pt) h[pt][o] = elus(z[pt][o]);
#pragma unroll
    for (int k = 0; k < 4; ++k)
#pragma unroll
        for (int pt = 0; pt < 2; ++pt) hp[pt][k] = pk(h[pt][2*k], h[pt][2*k+1]);

    float bm[2][4];
#pragma unroll
    for (int o = 0; o < 4; ++o) {
        float a[2] = { mb2[o], mb2[o] };
#pragma unroll
        for (int k = 0; k < 4; ++k) {
            h2 w = bits2h(W[OFF_MW2 + o*4 + k]);
#pragma unroll
            for (int pt = 0; pt < 2; ++pt) a[pt] = fdot2(hp[pt][k], w, a[pt]);
        }
        bm[0][o] = a[0]; bm[1][o] = a[1];
    }
    float m2[2], mag0[2], mag3[2];
#pragma unroll
    for (int pt = 0; pt < 2; ++pt) {
        m2[pt]   = bm[pt][0]*bm[pt][1] + bm[pt][2]*bm[pt][3];
        mag0[pt] = bm[pt][0]*bm[pt][0] + bm[pt][2]*bm[pt][2];
        mag3[pt] = bm[pt][1]*bm[pt][1] + bm[pt][3]*bm[pt][3];
    }

    // ---- p-branch: NV nets, fwd + analytic input-grad bwd ----
    float g0[2] = {0.f, 0.f}, g1[2] = {0.f, 0.f};
#pragma unroll
    for (int v = 0; v < NV; ++v) {
        float f1[2][8], f2[2][8];
        h2 f1p[2][4], f2p[2][4];
#pragma unroll
        for (int o = 0; o < 8; ++o) {
            h2 w = bits2h(W[OFF_PW1F + v*8 + o]);
            float b = Wf[FOFF_PB1 + v*8 + o];
#pragma unroll
            for (int pt = 0; pt < 2; ++pt) f1[pt][o] = fdot2(xh[pt], w, b);
        }
        tanh8s(f1[0]); tanh8s(f1[1]);
#pragma unroll
        for (int k = 0; k < 4; ++k)
#pragma unroll
            for (int pt = 0; pt < 2; ++pt) f1p[pt][k] = pk(f1[pt][2*k], f1[pt][2*k+1]);

#pragma unroll
        for (int q = 0; q < 8; ++q) {
            float b = Wf[FOFF_PB2 + v*8 + q];
            float a[2] = { b, b };
#pragma unroll
            for (int k = 0; k < 4; ++k) {
                h2 w = bits2h(W[OFF_PW2F + v*32 + q*4 + k]);
#pragma unroll
                for (int pt = 0; pt < 2; ++pt) a[pt] = fdot2(f1p[pt][k], w, a[pt]);
            }
            f2[0][q] = a[0]; f2[1][q] = a[1];
        }
        tanh8s(f2[0]); tanh8s(f2[1]);
#pragma unroll
        for (int k = 0; k < 4; ++k)
#pragma unroll
            for (int pt = 0; pt < 2; ++pt) f2p[pt][k] = pk(f2[pt][2*k], f2[pt][2*k+1]);

        float z3b = Wf[FOFF_PB3 + v];            // pre-scaled by -log2(e)
        float z3[2] = { z3b, z3b };
#pragma unroll
        for (int k = 0; k < 4; ++k) {
            h2 w = bits2h(W[OFF_PW3F + v*4 + k]);
#pragma unroll
            for (int pt = 0; pt < 2; ++pt) z3[pt] = fdot2(f2p[pt][k], w, z3[pt]);
        }
        float ss[2];
#pragma unroll
        for (int pt = 0; pt < 2; ++pt) {
            const float e1 = __builtin_amdgcn_exp2f(z3[pt]);       // 2^{-L2E*z3raw}
            const float f3 = __builtin_amdgcn_rcpf(e1 + 1.f);      // inner sigmoid (inf-clean)
            const float s  = sig01(f3);                            // outer: cubic
            ss[pt] = s * (1.f - s);
        }

        // t2 = 1 - f2^2, packed; W3 factor is pre-folded into V2T at prep.
        h2 t2p[2][4];
#pragma unroll
        for (int k = 0; k < 4; ++k)
#pragma unroll
            for (int pt = 0; pt < 2; ++pt)
                t2p[pt][k] = pk(fmaf(-f2[pt][2*k],   f2[pt][2*k],   1.f),
                                fmaf(-f2[pt][2*k+1], f2[pt][2*k+1], 1.f));

        // gp[p] = (sum_q W3[q](1-f2q^2) W2[q][p]) * (1 - f1[p]^2)
        float gp[2][8];
#pragma unroll
        for (int p = 0; p < 8; ++p) {
            float a[2] = { 0.f, 0.f };
#pragma unroll
            for (int k = 0; k < 4; ++k) {
                h2 w = bits2h(W[OFF_PW2T + v*32 + p*4 + k]);
#pragma unroll
                for (int pt = 0; pt < 2; ++pt) a[pt] = fdot2(t2p[pt][k], w, a[pt]);
            }
#pragma unroll
            for (int pt = 0; pt < 2; ++pt)
                gp[pt][p] = a[pt] * fmaf(-f1[pt][p], f1[pt][p], 1.f);
        }
        h2 gpp[2][4];
#pragma unroll
        for (int k = 0; k < 4; ++k)
#pragma unroll
            for (int pt = 0; pt < 2; ++pt) gpp[pt][k] = pk(gp[pt][2*k], gp[pt][2*k+1]);

        float gi0[2] = {0.f, 0.f}, gi1[2] = {0.f, 0.f};
#pragma unroll
        for (int k = 0; k < 4; ++k) {
            h2 w0 = bits2h(W[OFF_PW1T + v*8 + k]);
            h2 w1 = bits2h(W[OFF_PW1T + v*8 + 4 + k]);
#pragma unroll
            for (int pt = 0; pt < 2; ++pt) {
                gi0[pt] = fdot2(gpp[pt][k], w0, gi0[pt]);
                gi1[pt] = fdot2(gpp[pt][k], w1, gi1[pt]);
            }
        }
#pragma unroll
        for (int pt = 0; pt < 2; ++pt) {
            g0[pt] = fmaf(ss[pt], gi0[pt], g0[pt]);
            g1[pt] = fmaf(ss[pt], gi1[pt], g1[pt]);
        }
    }

    float r[2][2];
#pragma unroll
    for (int pt = 0; pt < 2; ++pt) {
        const float a = g0[pt] * 0.5f, b = g1[pt] * 0.5f;  // mean over NV=2
        r[pt][0] = mag0[pt]*a + m2[pt]*b;
        r[pt][1] = m2[pt]*a + mag3[pt]*b;
    }
    *reinterpret_cast<float4*>(out + b0 * 2) = make_float4(r[0][0], r[0][1], r[1][0], r[1][1]);
}

extern "C" void kernel_launch(void* const* d_in, const int* in_sizes, int n_in,
                              void* d_out, int out_size, void* d_ws, size_t ws_size,
                              hipStream_t stream) {
    // order: t, x, mW0, mb0, mW1, mb1, mW2, mb2, pW1, pb1, pW2, pb2, pW3, pb3
    const float* x   = (const float*)d_in[1];
    const float* mW0 = (const float*)d_in[2];
    const float* mb0 = (const float*)d_in[3];
    const float* mW1 = (const float*)d_in[4];
    const float* mb1 = (const float*)d_in[5];
    const float* mW2 = (const float*)d_in[6];
    const float* mb2 = (const float*)d_in[7];
    const float* pW1 = (const float*)d_in[8];
    const float* pb1 = (const float*)d_in[9];
    const float* pW2 = (const float*)d_in[10];
    const float* pb2 = (const float*)d_in[11];
    const float* pW3 = (const float*)d_in[12];
    const float* pb3 = (const float*)d_in[13];
    unsigned* ws = (unsigned*)d_ws;
    float* out = (float*)d_out;

    prep_kernel<<<1, 64, 0, stream>>>(mW0, mW1, mW2, pW1, pb1, pW2, pb2, pW3, pb3, ws);

    const int threads = 256;
    const int blocks  = NB / (threads * 2);   // 4096 blocks
    odefunc_kernel<<<blocks, threads, 0, stream>>>(x, ws, mb0, mb1, mb2, out);
}

// Round 9
// 131.166 us; speedup vs baseline: 1.4963x; 1.0312x over previous
//
#include <hip/hip_runtime.h>

#define NB 2097152
#define HM 8
#define HP 8
#define NV 2

// NOTE: clang's amdgcn builtins (cvt_pkrtz, fdot2) use __fp16 vectors.
typedef __fp16 h2 __attribute__((ext_vector_type(2)));

// Packed-weight workspace layout (32-bit words; h2 pairs unless noted f32):
#define OFF_MW0   0     // mW0p[8]        pairs over i (unscaled)
#define OFF_MW1   8     // mW1p[8][4]     pairs over i
#define OFF_MW2   40    // mW2p[4][4]     pairs over i
#define OFF_PW1F  56    // pW1f[v][8]     pairs over i, scaled 2*log2(e)
#define OFF_PW2F  72    // pW2f[v][8][4]  pairs over p, scaled 2*log2(e)
#define OFF_PW3F  136   // pW3f[v][4]     pairs over p, scaled -log2(e)
#define OFF_PW2T  144   // V2T[v][8][4]   pairs over q, = W3[q]*W2[q][p] (folded)
#define OFF_PW1T  208   // pW1T[v][2][4]  pairs over p (transposed, unscaled)
#define FOFF_PB1  224   // f32 2*log2(e)*pb1 [16]
#define FOFF_PB2  240   // f32 2*log2(e)*pb2 [16]
#define FOFF_PB3  256   // f32 -log2(e)*pb3 [2]

#define L2E  1.4426950408889634f
#define TL2E 2.8853901635333640f   // 2*log2(e)

static __device__ __forceinline__ h2 pk(float a, float b) {
    return __builtin_amdgcn_cvt_pkrtz(a, b);
}
static __device__ __forceinline__ float fdot2(h2 a, h2 b, float c) {
    return __builtin_amdgcn_fdot2(a, b, c, false);   // v_dot2_f32_f16
}
static __device__ __forceinline__ unsigned h2bits(h2 v) {
    union { h2 h; unsigned u; } c; c.h = v; return c.u;
}
static __device__ __forceinline__ h2 bits2h(unsigned u) {
    union { h2 h; unsigned u; } c; c.u = u; return c.h;
}
// v_pk_fma_f16: d = a*b + c, both halves in one instruction.
static __device__ __forceinline__ h2 pkfma(h2 a, h2 b, h2 c) {
    return __builtin_elementwise_fma(a, b, c);
}

// ---------------- prep: pack/scale weights into ws ----------------
__global__ void prep_kernel(
    const float* __restrict__ mW0, const float* __restrict__ mW1,
    const float* __restrict__ mW2,
    const float* __restrict__ pW1, const float* __restrict__ pb1,
    const float* __restrict__ pW2, const float* __restrict__ pb2,
    const float* __restrict__ pW3, const float* __restrict__ pb3,
    unsigned* __restrict__ ws)
{
    const int t = threadIdx.x;           // 64 threads
    float* wf = (float*)ws;

    if (t < 8)  ws[OFF_MW0 + t] = h2bits(pk(mW0[t*2], mW0[t*2+1]));
    if (t < 32) { int o = t >> 2, k = t & 3;
        ws[OFF_MW1 + t] = h2bits(pk(mW1[o*8 + 2*k], mW1[o*8 + 2*k + 1])); }
    if (t < 16) { int o = t >> 2, k = t & 3;
        ws[OFF_MW2 + t] = h2bits(pk(mW2[o*8 + 2*k], mW2[o*8 + 2*k + 1])); }
    if (t < 16) ws[OFF_PW1F + t] = h2bits(pk(TL2E*pW1[t*2], TL2E*pW1[t*2+1]));
    { int v = t >> 5, q = (t >> 2) & 7, k = t & 3;
      ws[OFF_PW2F + t] = h2bits(pk(TL2E*pW2[v*64 + q*8 + 2*k],
                                   TL2E*pW2[v*64 + q*8 + 2*k + 1])); }
    if (t < 8) { int v = t >> 2, k = t & 3;
        ws[OFF_PW3F + t] = h2bits(pk(-L2E*pW3[v*8 + 2*k], -L2E*pW3[v*8 + 2*k + 1])); }
    { // V2T: transposed W2 with W3 row-factor folded: pair over q of W3[q]*W2[q][p]
      int v = t >> 5, p = (t >> 2) & 7, k = t & 3;
      ws[OFF_PW2T + t] = h2bits(pk(pW3[v*8 + 2*k]     * pW2[v*64 + (2*k)*8 + p],
                                   pW3[v*8 + 2*k + 1] * pW2[v*64 + (2*k+1)*8 + p])); }
    if (t < 16) { int v = t >> 3, i = (t >> 2) & 1, k = t & 3;
        ws[OFF_PW1T + t] = h2bits(pk(pW1[v*16 + (2*k)*2 + i],
                                     pW1[v*16 + (2*k+1)*2 + i])); }
    if (t < 16) wf[FOFF_PB1 + t] = TL2E * pb1[t];
    if (t < 16) wf[FOFF_PB2 + t] = TL2E * pb2[t];
    if (t < 2)  wf[FOFF_PB3 + t] = -L2E * pb3[t];
}

// tanh from pre-scaled z (z = 2*log2(e)*x): tanh = 1 - 2*rcp(2^z + 1).
// Scalar part: exp2, add, rcp per value (overflow-clean: e=inf -> rcp=0 -> +1).
// Tail packed: pk(r pair) then ONE v_pk_fma_f16 (r*-2+1) per pair.
// Output: 4 f16 pairs directly (f32 f never materialized).
static __device__ __forceinline__ void tanh8p(const float* z, h2* outp) {
    const h2 m2h = { (__fp16)-2.f, (__fp16)-2.f };
    const h2 oneh = { (__fp16)1.f, (__fp16)1.f };
    float r[8];
#pragma unroll
    for (int i = 0; i < 8; ++i) {
        float e = __builtin_amdgcn_exp2f(z[i]);
        r[i] = __builtin_amdgcn_rcpf(e + 1.f);
    }
#pragma unroll
    for (int k = 0; k < 4; ++k)
        outp[k] = pkfma(pk(r[2*k], r[2*k+1]), m2h, oneh);
}
// elu(z) = med3(z, e^z - 1, 0). 4 ops. NaN-free.
static __device__ __forceinline__ float elus(float z) {
    float e = __builtin_amdgcn_exp2f(z * L2E);
    return __builtin_amdgcn_fmed3f(z, e - 1.f, 0.f);
}
// ss = s(1-s) with s = outer sigmoid of u in (0,1): s-0.5 = u*c(u) cubic fit,
// ss = 0.25 - (u*c(u))^2. 4 ops total.
static __device__ __forceinline__ float ss01(float u) {
    float c = fmaf(u, fmaf(u, -0.01566459f, -0.0040905f), 0.2508141f);
    float m = u * c;
    return fmaf(-m, m, 0.25f);
}

// Layer-lockstep: both points advance together; each weight s_loaded once.
__global__ __launch_bounds__(256, 4) void odefunc_kernel(
    const float* __restrict__ x,
    const unsigned* __restrict__ W,
    const float* __restrict__ mb0, const float* __restrict__ mb1,
    const float* __restrict__ mb2,
    float* __restrict__ out)
{
    const int tid = blockIdx.x * blockDim.x + threadIdx.x;
    const int b0  = tid * 2;                 // 2 points per thread, lockstep
    const float* Wf = (const float*)W;
    const h2 oneh = { (__fp16)1.f, (__fp16)1.f };

    const float4 xv = *reinterpret_cast<const float4*>(x + b0 * 2);
    h2 xh[2] = { pk(xv.x, xv.y), pk(xv.z, xv.w) };

    // ---- m-branch: 2 -> 8 -> 8 -> 4, ELU ----
    float z[2][8], h[2][8];
    h2 hp[2][4];
#pragma unroll
    for (int o = 0; o < 8; ++o) {
        h2 w = bits2h(W[OFF_MW0 + o]);
#pragma unroll
        for (int pt = 0; pt < 2; ++pt) z[pt][o] = fdot2(xh[pt], w, mb0[o]);
    }
#pragma unroll
    for (int o = 0; o < 8; ++o)
#pragma unroll
        for (int pt = 0; pt < 2; ++pt) h[pt][o] = elus(z[pt][o]);
#pragma unroll
    for (int k = 0; k < 4; ++k)
#pragma unroll
        for (int pt = 0; pt < 2; ++pt) hp[pt][k] = pk(h[pt][2*k], h[pt][2*k+1]);

#pragma unroll
    for (int o = 0; o < 8; ++o) {
        float a[2] = { mb1[o], mb1[o] };
#pragma unroll
        for (int k = 0; k < 4; ++k) {
            h2 w = bits2h(W[OFF_MW1 + o*4 + k]);
#pragma unroll
            for (int pt = 0; pt < 2; ++pt) a[pt] = fdot2(hp[pt][k], w, a[pt]);
        }
        z[0][o] = a[0]; z[1][o] = a[1];
    }
#pragma unroll
    for (int o = 0; o < 8; ++o)
#pragma unroll
        for (int pt = 0; pt < 2; ++pt) h[pt][o] = elus(z[pt][o]);
#pragma unroll
    for (int k = 0; k < 4; ++k)
#pragma unroll
        for (int pt = 0; pt < 2; ++pt) hp[pt][k] = pk(h[pt][2*k], h[pt][2*k+1]);

    float bm[2][4];
#pragma unroll
    for (int o = 0; o < 4; ++o) {
        float a[2] = { mb2[o], mb2[o] };
#pragma unroll
        for (int k = 0; k < 4; ++k) {
            h2 w = bits2h(W[OFF_MW2 + o*4 + k]);
#pragma unroll
            for (int pt = 0; pt < 2; ++pt) a[pt] = fdot2(hp[pt][k], w, a[pt]);
        }
        bm[0][o] = a[0]; bm[1][o] = a[1];
    }
    float m2[2], mag0[2], mag3[2];
#pragma unroll
    for (int pt = 0; pt < 2; ++pt) {
        m2[pt]   = bm[pt][0]*bm[pt][1] + bm[pt][2]*bm[pt][3];
        mag0[pt] = bm[pt][0]*bm[pt][0] + bm[pt][2]*bm[pt][2];
        mag3[pt] = bm[pt][1]*bm[pt][1] + bm[pt][3]*bm[pt][3];
    }

    // ---- p-branch: NV nets, fwd + analytic input-grad bwd ----
    float g0[2] = {0.f, 0.f}, g1[2] = {0.f, 0.f};
#pragma unroll
    for (int v = 0; v < NV; ++v) {
        float zf[2][8];
        h2 f1p[2][4], f2p[2][4];
#pragma unroll
        for (int o = 0; o < 8; ++o) {
            h2 w = bits2h(W[OFF_PW1F + v*8 + o]);
            float b = Wf[FOFF_PB1 + v*8 + o];
#pragma unroll
            for (int pt = 0; pt < 2; ++pt) zf[pt][o] = fdot2(xh[pt], w, b);
        }
        tanh8p(zf[0], f1p[0]); tanh8p(zf[1], f1p[1]);

#pragma unroll
        for (int q = 0; q < 8; ++q) {
            float b = Wf[FOFF_PB2 + v*8 + q];
            float a[2] = { b, b };
#pragma unroll
            for (int k = 0; k < 4; ++k) {
                h2 w = bits2h(W[OFF_PW2F + v*32 + q*4 + k]);
#pragma unroll
                for (int pt = 0; pt < 2; ++pt) a[pt] = fdot2(f1p[pt][k], w, a[pt]);
            }
            zf[0][q] = a[0]; zf[1][q] = a[1];
        }
        tanh8p(zf[0], f2p[0]); tanh8p(zf[1], f2p[1]);

        float z3b = Wf[FOFF_PB3 + v];            // pre-scaled by -log2(e)
        float z3[2] = { z3b, z3b };
#pragma unroll
        for (int k = 0; k < 4; ++k) {
            h2 w = bits2h(W[OFF_PW3F + v*4 + k]);
#pragma unroll
            for (int pt = 0; pt < 2; ++pt) z3[pt] = fdot2(f2p[pt][k], w, z3[pt]);
        }
        float ss[2];
#pragma unroll
        for (int pt = 0; pt < 2; ++pt) {
            const float e1 = __builtin_amdgcn_exp2f(z3[pt]);       // 2^{-L2E*z3raw}
            const float f3 = __builtin_amdgcn_rcpf(e1 + 1.f);      // inner sigmoid
            ss[pt] = ss01(f3);                                     // outer s(1-s), 4 ops
        }

        // t2 = 1 - f2^2, entirely packed: one v_pk_fma_f16 per pair.
        h2 t2p[2][4];
#pragma unroll
        for (int k = 0; k < 4; ++k)
#pragma unroll
            for (int pt = 0; pt < 2; ++pt)
                t2p[pt][k] = pkfma(-f2p[pt][k], f2p[pt][k], oneh);

        // a[p] = sum_q W3[q](1-f2q^2) W2[q][p]  (W3 folded into V2T at prep)
        float ga[2][8];
#pragma unroll
        for (int p = 0; p < 8; ++p) {
            float a[2] = { 0.f, 0.f };
#pragma unroll
            for (int k = 0; k < 4; ++k) {
                h2 w = bits2h(W[OFF_PW2T + v*32 + p*4 + k]);
#pragma unroll
                for (int pt = 0; pt < 2; ++pt) a[pt] = fdot2(t2p[pt][k], w, a[pt]);
            }
            ga[0][p] = a[0]; ga[1][p] = a[1];
        }
        // gpp = pk(a) * (1 - f1^2), packed: pk + pk_fma + pk_mul per pair.
        h2 gpp[2][4];
#pragma unroll
        for (int k = 0; k < 4; ++k)
#pragma unroll
            for (int pt = 0; pt < 2; ++pt) {
                h2 t1 = pkfma(-f1p[pt][k], f1p[pt][k], oneh);
                gpp[pt][k] = pk(ga[pt][2*k], ga[pt][2*k+1]) * t1;
            }

        float gi0[2] = {0.f, 0.f}, gi1[2] = {0.f, 0.f};
#pragma unroll
        for (int k = 0; k < 4; ++k) {
            h2 w0 = bits2h(W[OFF_PW1T + v*8 + k]);
            h2 w1 = bits2h(W[OFF_PW1T + v*8 + 4 + k]);
#pragma unroll
            for (int pt = 0; pt < 2; ++pt) {
                gi0[pt] = fdot2(gpp[pt][k], w0, gi0[pt]);
                gi1[pt] = fdot2(gpp[pt][k], w1, gi1[pt]);
            }
        }
#pragma unroll
        for (int pt = 0; pt < 2; ++pt) {
            g0[pt] = fmaf(ss[pt], gi0[pt], g0[pt]);
            g1[pt] = fmaf(ss[pt], gi1[pt], g1[pt]);
        }
    }

    float r[2][2];
#pragma unroll
    for (int pt = 0; pt < 2; ++pt) {
        const float a = g0[pt] * 0.5f, b = g1[pt] * 0.5f;  // mean over NV=2
        r[pt][0] = mag0[pt]*a + m2[pt]*b;
        r[pt][1] = m2[pt]*a + mag3[pt]*b;
    }
    *reinterpret_cast<float4*>(out + b0 * 2) = make_float4(r[0][0], r[0][1], r[1][0], r[1][1]);
}

extern "C" void kernel_launch(void* const* d_in, const int* in_sizes, int n_in,
                              void* d_out, int out_size, void* d_ws, size_t ws_size,
                              hipStream_t stream) {
    // order: t, x, mW0, mb0, mW1, mb1, mW2, mb2, pW1, pb1, pW2, pb2, pW3, pb3
    const float* x   = (const float*)d_in[1];
    const float* mW0 = (const float*)d_in[2];
    const float* mb0 = (const float*)d_in[3];
    const float* mW1 = (const float*)d_in[4];
    const float* mb1 = (const float*)d_in[5];
    const float* mW2 = (const float*)d_in[6];
    const float* mb2 = (const float*)d_in[7];
    const float* pW1 = (const float*)d_in[8];
    const float* pb1 = (const float*)d_in[9];
    const float* pW2 = (const float*)d_in[10];
    const float* pb2 = (const float*)d_in[11];
    const float* pW3 = (const float*)d_in[12];
    const float* pb3 = (const float*)d_in[13];
    unsigned* ws = (unsigned*)d_ws;
    float* out = (float*)d_out;

    prep_kernel<<<1, 64, 0, stream>>>(mW0, mW1, mW2, pW1, pb1, pW2, pb2, pW3, pb3, ws);

    const int threads = 256;
    const int blocks  = NB / (threads * 2);   // 4096 blocks
    odefunc_kernel<<<blocks, threads, 0, stream>>>(x, ws, mb0, mb1, mb2, out);
}

// Round 10
// 129.361 us; speedup vs baseline: 1.5172x; 1.0139x over previous
//
#include <hip/hip_runtime.h>

#define NB 2097152
#define HM 8
#define HP 8
#define NV 2

// NOTE: clang's amdgcn builtins (cvt_pkrtz, fdot2) use __fp16 vectors.
typedef __fp16 h2 __attribute__((ext_vector_type(2)));

// Packed-weight workspace layout (32-bit words; h2 pairs unless noted f32):
#define OFF_MW0   0     // mW0p[8]        pairs over i, scaled log2(e)  (ELU fold)
#define OFF_MW1   8     // mW1p[8][4]     pairs over i, UNSCALED (L2E*ln2 cancels)
#define OFF_MW2   40    // mW2p[4][4]     pairs over i, scaled ln2 (undo h-tilde)
#define OFF_PW1F  56    // pW1f[v][8]     pairs over i, scaled 2*log2(e) (tanh fold)
#define OFF_PW2F  72    // pW2f[v][8][4]  pairs over p, scaled 2*log2(e)
#define OFF_PW3F  136   // pW3f[v][4]     pairs over p, scaled -log2(e)  (sigmoid fold)
#define OFF_PW2T  144   // V2T[v][8][4]   pairs over q, = 0.5*W3[q]*W2[q][p] (W3+mean fold)
#define OFF_PW1T  208   // pW1T[v][2][4]  pairs over p (transposed, unscaled)
#define FOFF_PB1  224   // f32 2*log2(e)*pb1 [16]
#define FOFF_PB2  240   // f32 2*log2(e)*pb2 [16]
#define FOFF_PB3  256   // f32 -log2(e)*pb3 [2]
#define FOFF_MB0  260   // f32 log2(e)*mb0 [8]
#define FOFF_MB1  268   // f32 log2(e)*mb1 [8]

#define L2E  1.4426950408889634f
#define LN2  0.6931471805599453f
#define TL2E 2.8853901635333640f   // 2*log2(e)

static __device__ __forceinline__ h2 pk(float a, float b) {
    return __builtin_amdgcn_cvt_pkrtz(a, b);
}
static __device__ __forceinline__ float fdot2(h2 a, h2 b, float c) {
    return __builtin_amdgcn_fdot2(a, b, c, false);   // v_dot2_f32_f16
}
static __device__ __forceinline__ unsigned h2bits(h2 v) {
    union { h2 h; unsigned u; } c; c.h = v; return c.u;
}
static __device__ __forceinline__ h2 bits2h(unsigned u) {
    union { h2 h; unsigned u; } c; c.u = u; return c.h;
}
static __device__ __forceinline__ h2 pkfma(h2 a, h2 b, h2 c) {
    return __builtin_elementwise_fma(a, b, c);       // v_pk_fma_f16
}

// ---------------- prep: pack/scale weights into ws ----------------
__global__ void prep_kernel(
    const float* __restrict__ mW0, const float* __restrict__ mb0,
    const float* __restrict__ mW1, const float* __restrict__ mb1,
    const float* __restrict__ mW2,
    const float* __restrict__ pW1, const float* __restrict__ pb1,
    const float* __restrict__ pW2, const float* __restrict__ pb2,
    const float* __restrict__ pW3, const float* __restrict__ pb3,
    unsigned* __restrict__ ws)
{
    const int t = threadIdx.x;           // 64 threads
    float* wf = (float*)ws;

    // ELU scale-fold: layer0 weights/bias *L2E; layer1 weights unscaled
    // (absorbs ln2 from h-tilde, emits L2E for its own elu: cancels), bias *L2E;
    // layer2 weights *ln2 (pure absorb), bias raw.
    if (t < 8)  ws[OFF_MW0 + t] = h2bits(pk(L2E*mW0[t*2], L2E*mW0[t*2+1]));
    if (t < 32) { int o = t >> 2, k = t & 3;
        ws[OFF_MW1 + t] = h2bits(pk(mW1[o*8 + 2*k], mW1[o*8 + 2*k + 1])); }
    if (t < 16) { int o = t >> 2, k = t & 3;
        ws[OFF_MW2 + t] = h2bits(pk(LN2*mW2[o*8 + 2*k], LN2*mW2[o*8 + 2*k + 1])); }
    if (t < 16) ws[OFF_PW1F + t] = h2bits(pk(TL2E*pW1[t*2], TL2E*pW1[t*2+1]));
    { int v = t >> 5, q = (t >> 2) & 7, k = t & 3;
      ws[OFF_PW2F + t] = h2bits(pk(TL2E*pW2[v*64 + q*8 + 2*k],
                                   TL2E*pW2[v*64 + q*8 + 2*k + 1])); }
    if (t < 8) { int v = t >> 2, k = t & 3;
        ws[OFF_PW3F + t] = h2bits(pk(-L2E*pW3[v*8 + 2*k], -L2E*pW3[v*8 + 2*k + 1])); }
    { // V2T: transposed W2, W3 row-factor AND the NV-mean 0.5 folded in.
      int v = t >> 5, p = (t >> 2) & 7, k = t & 3;
      ws[OFF_PW2T + t] = h2bits(pk(0.5f*pW3[v*8 + 2*k]     * pW2[v*64 + (2*k)*8 + p],
                                   0.5f*pW3[v*8 + 2*k + 1] * pW2[v*64 + (2*k+1)*8 + p])); }
    if (t < 16) { int v = t >> 3, i = (t >> 2) & 1, k = t & 3;
        ws[OFF_PW1T + t] = h2bits(pk(pW1[v*16 + (2*k)*2 + i],
                                     pW1[v*16 + (2*k+1)*2 + i])); }
    if (t < 16) wf[FOFF_PB1 + t] = TL2E * pb1[t];
    if (t < 16) wf[FOFF_PB2 + t] = TL2E * pb2[t];
    if (t < 2)  wf[FOFF_PB3 + t] = -L2E * pb3[t];
    if (t < 8)  wf[FOFF_MB0 + t] = L2E * mb0[t];
    if (t < 8)  wf[FOFF_MB1 + t] = L2E * mb1[t];
}

// tanh from pre-scaled z: tanh = 1 - 2*rcp(2^z + 1); tail packed (1 pkfma/pair).
static __device__ __forceinline__ void tanh8p(const float* z, h2* outp) {
    const h2 m2h = { (__fp16)-2.f, (__fp16)-2.f };
    const h2 oneh = { (__fp16)1.f, (__fp16)1.f };
    float r[8];
#pragma unroll
    for (int i = 0; i < 8; ++i) {
        float e = __builtin_amdgcn_exp2f(z[i]);
        r[i] = __builtin_amdgcn_rcpf(e + 1.f);
    }
#pragma unroll
    for (int k = 0; k < 4; ++k)
        outp[k] = pkfma(pk(r[2*k], r[2*k+1]), m2h, oneh);
}
// Scaled ELU on pre-scaled z' (= L2E*z): returns L2E*elu(z) =
// med3(z', L2E*2^{z'} - L2E, 0). 3 ops: exp2, fma, med3. NaN-free.
static __device__ __forceinline__ float elus(float zp) {
    float e = __builtin_amdgcn_exp2f(zp);
    return __builtin_amdgcn_fmed3f(zp, fmaf(e, L2E, -L2E), 0.f);
}
// ss = s(1-s), s = outer sigmoid of u in (0,1): s-0.5 = u*c(u) cubic fit.
static __device__ __forceinline__ float ss01(float u) {
    float c = fmaf(u, fmaf(u, -0.01566459f, -0.0040905f), 0.2508141f);
    float m = u * c;
    return fmaf(-m, m, 0.25f);
}

// Layer-lockstep: both points advance together; each weight s_loaded once.
__global__ __launch_bounds__(256, 4) void odefunc_kernel(
    const float* __restrict__ x,
    const unsigned* __restrict__ W,
    const float* __restrict__ mb2,
    float* __restrict__ out)
{
    const int tid = blockIdx.x * blockDim.x + threadIdx.x;
    const int b0  = tid * 2;                 // 2 points per thread, lockstep
    const float* Wf = (const float*)W;
    const h2 oneh = { (__fp16)1.f, (__fp16)1.f };

    const float4 xv = *reinterpret_cast<const float4*>(x + b0 * 2);
    h2 xh[2] = { pk(xv.x, xv.y), pk(xv.z, xv.w) };

    // ---- m-branch: 2 -> 8 -> 8 -> 4, scaled-ELU chain ----
    float z[2][8], h[2][8];
    h2 hp[2][4];
#pragma unroll
    for (int o = 0; o < 8; ++o) {
        h2 w = bits2h(W[OFF_MW0 + o]);
        float b = Wf[FOFF_MB0 + o];
#pragma unroll
        for (int pt = 0; pt < 2; ++pt) z[pt][o] = fdot2(xh[pt], w, b);
    }
#pragma unroll
    for (int o = 0; o < 8; ++o)
#pragma unroll
        for (int pt = 0; pt < 2; ++pt) h[pt][o] = elus(z[pt][o]);
#pragma unroll
    for (int k = 0; k < 4; ++k)
#pragma unroll
        for (int pt = 0; pt < 2; ++pt) hp[pt][k] = pk(h[pt][2*k], h[pt][2*k+1]);

#pragma unroll
    for (int o = 0; o < 8; ++o) {
        float b = Wf[FOFF_MB1 + o];
        float a[2] = { b, b };
#pragma unroll
        for (int k = 0; k < 4; ++k) {
            h2 w = bits2h(W[OFF_MW1 + o*4 + k]);
#pragma unroll
            for (int pt = 0; pt < 2; ++pt) a[pt] = fdot2(hp[pt][k], w, a[pt]);
        }
        z[0][o] = a[0]; z[1][o] = a[1];
    }
#pragma unroll
    for (int o = 0; o < 8; ++o)
#pragma unroll
        for (int pt = 0; pt < 2; ++pt) h[pt][o] = elus(z[pt][o]);
#pragma unroll
    for (int k = 0; k < 4; ++k)
#pragma unroll
        for (int pt = 0; pt < 2; ++pt) hp[pt][k] = pk(h[pt][2*k], h[pt][2*k+1]);

    float bm[2][4];
#pragma unroll
    for (int o = 0; o < 4; ++o) {
        float a[2] = { mb2[o], mb2[o] };
#pragma unroll
        for (int k = 0; k < 4; ++k) {
            h2 w = bits2h(W[OFF_MW2 + o*4 + k]);
#pragma unroll
            for (int pt = 0; pt < 2; ++pt) a[pt] = fdot2(hp[pt][k], w, a[pt]);
        }
        bm[0][o] = a[0]; bm[1][o] = a[1];
    }
    float m2[2], mag0[2], mag3[2];
#pragma unroll
    for (int pt = 0; pt < 2; ++pt) {
        m2[pt]   = bm[pt][0]*bm[pt][1] + bm[pt][2]*bm[pt][3];
        mag0[pt] = bm[pt][0]*bm[pt][0] + bm[pt][2]*bm[pt][2];
        mag3[pt] = bm[pt][1]*bm[pt][1] + bm[pt][3]*bm[pt][3];
    }

    // ---- p-branch: NV nets, fwd + analytic input-grad bwd ----
    float g0[2] = {0.f, 0.f}, g1[2] = {0.f, 0.f};
#pragma unroll
    for (int v = 0; v < NV; ++v) {
        float zf[2][8];
        h2 f1p[2][4], f2p[2][4];
#pragma unroll
        for (int o = 0; o < 8; ++o) {
            h2 w = bits2h(W[OFF_PW1F + v*8 + o]);
            float b = Wf[FOFF_PB1 + v*8 + o];
#pragma unroll
            for (int pt = 0; pt < 2; ++pt) zf[pt][o] = fdot2(xh[pt], w, b);
        }
        tanh8p(zf[0], f1p[0]); tanh8p(zf[1], f1p[1]);

#pragma unroll
        for (int q = 0; q < 8; ++q) {
            float b = Wf[FOFF_PB2 + v*8 + q];
            float a[2] = { b, b };
#pragma unroll
            for (int k = 0; k < 4; ++k) {
                h2 w = bits2h(W[OFF_PW2F + v*32 + q*4 + k]);
#pragma unroll
                for (int pt = 0; pt < 2; ++pt) a[pt] = fdot2(f1p[pt][k], w, a[pt]);
            }
            zf[0][q] = a[0]; zf[1][q] = a[1];
        }
        tanh8p(zf[0], f2p[0]); tanh8p(zf[1], f2p[1]);

        float z3b = Wf[FOFF_PB3 + v];            // pre-scaled by -log2(e)
        float z3[2] = { z3b, z3b };
#pragma unroll
        for (int k = 0; k < 4; ++k) {
            h2 w = bits2h(W[OFF_PW3F + v*4 + k]);
#pragma unroll
            for (int pt = 0; pt < 2; ++pt) z3[pt] = fdot2(f2p[pt][k], w, z3[pt]);
        }
        float ss[2];
#pragma unroll
        for (int pt = 0; pt < 2; ++pt) {
            const float e1 = __builtin_amdgcn_exp2f(z3[pt]);
            const float f3 = __builtin_amdgcn_rcpf(e1 + 1.f);   // inner sigmoid
            ss[pt] = ss01(f3);                                  // outer s(1-s)
        }

        // t2 = 1 - f2^2, packed: one v_pk_fma_f16 per pair.
        h2 t2p[2][4];
#pragma unroll
        for (int k = 0; k < 4; ++k)
#pragma unroll
            for (int pt = 0; pt < 2; ++pt)
                t2p[pt][k] = pkfma(-f2p[pt][k], f2p[pt][k], oneh);

        // a[p] = sum_q 0.5*W3[q](1-f2q^2) W2[q][p]  (W3+mean folded into V2T)
        float ga[2][8];
#pragma unroll
        for (int p = 0; p < 8; ++p) {
            float a[2] = { 0.f, 0.f };
#pragma unroll
            for (int k = 0; k < 4; ++k) {
                h2 w = bits2h(W[OFF_PW2T + v*32 + p*4 + k]);
#pragma unroll
                for (int pt = 0; pt < 2; ++pt) a[pt] = fdot2(t2p[pt][k], w, a[pt]);
            }
            ga[0][p] = a[0]; ga[1][p] = a[1];
        }
        h2 gpp[2][4];
#pragma unroll
        for (int k = 0; k < 4; ++k)
#pragma unroll
            for (int pt = 0; pt < 2; ++pt) {
                h2 t1 = pkfma(-f1p[pt][k], f1p[pt][k], oneh);
                gpp[pt][k] = pk(ga[pt][2*k], ga[pt][2*k+1]) * t1;
            }

        float gi0[2] = {0.f, 0.f}, gi1[2] = {0.f, 0.f};
#pragma unroll
        for (int k = 0; k < 4; ++k) {
            h2 w0 = bits2h(W[OFF_PW1T + v*8 + k]);
            h2 w1 = bits2h(W[OFF_PW1T + v*8 + 4 + k]);
#pragma unroll
            for (int pt = 0; pt < 2; ++pt) {
                gi0[pt] = fdot2(gpp[pt][k], w0, gi0[pt]);
                gi1[pt] = fdot2(gpp[pt][k], w1, gi1[pt]);
            }
        }
#pragma unroll
        for (int pt = 0; pt < 2; ++pt) {
            g0[pt] = fmaf(ss[pt], gi0[pt], g0[pt]);
            g1[pt] = fmaf(ss[pt], gi1[pt], g1[pt]);
        }
    }

    float r[2][2];
#pragma unroll
    for (int pt = 0; pt < 2; ++pt) {       // 0.5 mean already folded into V2T
        r[pt][0] = mag0[pt]*g0[pt] + m2[pt]*g1[pt];
        r[pt][1] = m2[pt]*g0[pt] + mag3[pt]*g1[pt];
    }
    *reinterpret_cast<float4*>(out + b0 * 2) = make_float4(r[0][0], r[0][1], r[1][0], r[1][1]);
}

extern "C" void kernel_launch(void* const* d_in, const int* in_sizes, int n_in,
                              void* d_out, int out_size, void* d_ws, size_t ws_size,
                              hipStream_t stream) {
    // order: t, x, mW0, mb0, mW1, mb1, mW2, mb2, pW1, pb1, pW2, pb2, pW3, pb3
    const float* x   = (const float*)d_in[1];
    const float* mW0 = (const float*)d_in[2];
    const float* mb0 = (const float*)d_in[3];
    const float* mW1 = (const float*)d_in[4];
    const float* mb1 = (const float*)d_in[5];
    const float* mW2 = (const float*)d_in[6];
    const float* mb2 = (const float*)d_in[7];
    const float* pW1 = (const float*)d_in[8];
    const float* pb1 = (const float*)d_in[9];
    const float* pW2 = (const float*)d_in[10];
    const float* pb2 = (const float*)d_in[11];
    const float* pW3 = (const float*)d_in[12];
    const float* pb3 = (const float*)d_in[13];
    unsigned* ws = (unsigned*)d_ws;
    float* out = (float*)d_out;

    prep_kernel<<<1, 64, 0, stream>>>(mW0, mb0, mW1, mb1, mW2,
                                      pW1, pb1, pW2, pb2, pW3, pb3, ws);

    const int threads = 256;
    const int blocks  = NB / (threads * 2);   // 4096 blocks
    odefunc_kernel<<<blocks, threads, 0, stream>>>(x, ws, mb2, out);
}